// Round 10
// baseline (306.379 us; speedup 1.0000x reference)
//
#include <hip/hip_runtime.h>
#include <math.h>

typedef __attribute__((ext_vector_type(8))) short short8;
typedef __attribute__((ext_vector_type(4))) float f32x4;
typedef __attribute__((ext_vector_type(2))) unsigned int uint2v;

#define DEV __device__ __forceinline__

static constexpr int B_ = 4, C_ = 256, S_ = 2048, H_ = 8, O3_ = 768;
static constexpr int TOPK = 512;
static constexpr int QT = 16;           // q rows per workgroup in attention
static constexpr int QCOLS = 512;       // score cols staged per quarter pass
static constexpr int QSTR = 516;        // fp32 score row stride (quarter buffer)
static constexpr int HCOLS = 1024;      // P half cols
static constexpr int PSTH = 1024;       // bf16 P half row stride; rows 2048B-aligned -> XOR swizzle bijective
// LDS: one region, 16*516*4 = 33024 B. Half-P (16*1024*2=32768 B) and red (8*529*4=16928 B) alias it.
// 512-thread WG -> 4 WGs/CU (132 KB), 32 waves/CU.
static constexpr size_t K3_LDS_BYTES = (size_t)QT * QSTR * 4;  // 33024 B

DEV unsigned cvt_pk_bf16(float a, float b) {
  unsigned r;
  asm("v_cvt_pk_bf16_f32 %0, %1, %2" : "=v"(r) : "v"(a), "v"(b));
  return r;  // lo16 = bf16(a), hi16 = bf16(b)
}
DEV unsigned short f2bf1(float f) { return (unsigned short)(cvt_pk_bf16(f, f) & 0xFFFFu); }
DEV float bf2f(unsigned short h) { return __uint_as_float(((unsigned)h) << 16); }
DEV void hilo(float f, unsigned short& h, unsigned short& l) {
  unsigned p = cvt_pk_bf16(f, f);
  h = (unsigned short)p;
  float r = f - __uint_as_float(p << 16);
  l = (unsigned short)(cvt_pk_bf16(r, r) & 0xFFFFu);
}

// ---------------- K0a: weights -> bf16 hi/lo (qkv), bf16 (proj) ----------------
__global__ void k_convw(const float* __restrict__ wqkv, const float* __restrict__ wproj,
                        unsigned short* __restrict__ wq_hi, unsigned short* __restrict__ wq_lo,
                        unsigned short* __restrict__ wproj_bf) {
  int i = blockIdx.x * 256 + threadIdx.x;
  if (i < O3_ * C_) {
    unsigned short h, l;
    hilo(wqkv[i], h, l);
    wq_hi[i] = h;
    wq_lo[i] = l;
  }
  if (i < C_ * C_) wproj_bf[i] = f2bf1(wproj[i]);
}

// ---------------- K0b: transpose x [b][c][s] -> xT hi/lo bf16 [b][s][c] ----------------
__global__ void k_xt(const float* __restrict__ x, unsigned short* __restrict__ xT_hi,
                     unsigned short* __restrict__ xT_lo) {
  __shared__ float t[32][33];
  int b = blockIdx.z;
  int c0 = blockIdx.y * 32, s0 = blockIdx.x * 32;
  int tx = threadIdx.x, ty = threadIdx.y;
  const float* xb = x + (size_t)b * C_ * S_;
#pragma unroll
  for (int j = 0; j < 4; ++j)
    t[ty + 8 * j][tx] = xb[(size_t)(c0 + ty + 8 * j) * S_ + s0 + tx];
  __syncthreads();
  unsigned short* hb = xT_hi + (size_t)b * S_ * C_;
  unsigned short* lb = xT_lo + (size_t)b * S_ * C_;
#pragma unroll
  for (int j = 0; j < 4; ++j) {
    unsigned short h, l;
    hilo(t[tx][ty + 8 * j], h, l);
    size_t o = (size_t)(s0 + ty + 8 * j) * C_ + c0 + tx;
    hb[o] = h;
    lb[o] = l;
  }
}

// ---------------- K1: qkv_raw = W_qkv @ x  (split-bf16 3-pass MFMA, ~fp32 accurate) ----------------
__global__ __launch_bounds__(256) void k_qkv(const unsigned short* __restrict__ w_hi,
                                             const unsigned short* __restrict__ w_lo,
                                             const unsigned short* __restrict__ x_hi,
                                             const unsigned short* __restrict__ x_lo,
                                             float* __restrict__ raw) {
  int b = blockIdx.z;
  int m0 = blockIdx.y * 64, n0 = blockIdx.x * 64;
  int tid = threadIdx.x, lane = tid & 63, wid = tid >> 6;
  int l15 = lane & 15, lh = lane >> 4;
  int wm = (wid >> 1) * 32, wn = (wid & 1) * 32;
  const unsigned short* xhb = x_hi + (size_t)b * S_ * C_;
  const unsigned short* xlb = x_lo + (size_t)b * S_ * C_;
  f32x4 acc[2][2] = {};
  int mA = m0 + wm + l15;
  int nB = n0 + wn + l15;
  for (int k0 = 0; k0 < C_; k0 += 32) {
    int kk = k0 + lh * 8;
    short8 a0h = *(const short8*)(w_hi + (size_t)mA * C_ + kk);
    short8 a1h = *(const short8*)(w_hi + (size_t)(mA + 16) * C_ + kk);
    short8 a0l = *(const short8*)(w_lo + (size_t)mA * C_ + kk);
    short8 a1l = *(const short8*)(w_lo + (size_t)(mA + 16) * C_ + kk);
    short8 b0h = *(const short8*)(xhb + (size_t)nB * C_ + kk);
    short8 b1h = *(const short8*)(xhb + (size_t)(nB + 16) * C_ + kk);
    short8 b0l = *(const short8*)(xlb + (size_t)nB * C_ + kk);
    short8 b1l = *(const short8*)(xlb + (size_t)(nB + 16) * C_ + kk);
    acc[0][0] = __builtin_amdgcn_mfma_f32_16x16x32_bf16(a0h, b0h, acc[0][0], 0, 0, 0);
    acc[0][1] = __builtin_amdgcn_mfma_f32_16x16x32_bf16(a0h, b1h, acc[0][1], 0, 0, 0);
    acc[1][0] = __builtin_amdgcn_mfma_f32_16x16x32_bf16(a1h, b0h, acc[1][0], 0, 0, 0);
    acc[1][1] = __builtin_amdgcn_mfma_f32_16x16x32_bf16(a1h, b1h, acc[1][1], 0, 0, 0);
    acc[0][0] = __builtin_amdgcn_mfma_f32_16x16x32_bf16(a0h, b0l, acc[0][0], 0, 0, 0);
    acc[0][1] = __builtin_amdgcn_mfma_f32_16x16x32_bf16(a0h, b1l, acc[0][1], 0, 0, 0);
    acc[1][0] = __builtin_amdgcn_mfma_f32_16x16x32_bf16(a1h, b0l, acc[1][0], 0, 0, 0);
    acc[1][1] = __builtin_amdgcn_mfma_f32_16x16x32_bf16(a1h, b1l, acc[1][1], 0, 0, 0);
    acc[0][0] = __builtin_amdgcn_mfma_f32_16x16x32_bf16(a0l, b0h, acc[0][0], 0, 0, 0);
    acc[0][1] = __builtin_amdgcn_mfma_f32_16x16x32_bf16(a0l, b1h, acc[0][1], 0, 0, 0);
    acc[1][0] = __builtin_amdgcn_mfma_f32_16x16x32_bf16(a1l, b0h, acc[1][0], 0, 0, 0);
    acc[1][1] = __builtin_amdgcn_mfma_f32_16x16x32_bf16(a1l, b1h, acc[1][1], 0, 0, 0);
  }
  float* rawb = raw + (size_t)b * O3_ * S_;
#pragma unroll
  for (int i = 0; i < 2; ++i)
#pragma unroll
    for (int j = 0; j < 2; ++j)
#pragma unroll
      for (int r = 0; r < 4; ++r) {
        int row = m0 + wm + i * 16 + lh * 4 + r;
        int col = n0 + wn + j * 16 + l15;
        rawb[(size_t)row * S_ + col] = acc[i][j][r];
      }
}

// ---------------- K2: depthwise conv + head split + l2norm (+temperature fold) ----------------
DEV float conv3(const float* __restrict__ rp, const float* __restrict__ w, int s) {
  float a = (s > 0) ? rp[s - 1] : 0.f;
  float b = rp[s];
  float c = (s < S_ - 1) ? rp[s + 1] : 0.f;
  return w[0] * a + w[1] * b + w[2] * c;
}

__global__ __launch_bounds__(256) void k_dwnorm(const float* __restrict__ raw,
                                                const float* __restrict__ wdw,
                                                const float* __restrict__ temp,
                                                unsigned short* __restrict__ q_hi,
                                                unsigned short* __restrict__ q_lo,
                                                unsigned short* __restrict__ k_hi,
                                                unsigned short* __restrict__ k_lo,
                                                unsigned short* __restrict__ vt) {
  int b = blockIdx.z, h = blockIdx.y;
  int tid = threadIdx.x;
  int wave = tid >> 6, lane = tid & 63;
  int dg = lane & 7;        // d-group (4 d's each)
  int sl = lane >> 3;       // s within wave
  int s = blockIdx.x * 32 + wave * 8 + sl;
  const float* rawb = raw + (size_t)b * O3_ * S_;
  float tph = temp[h];
  size_t bh = (size_t)(b * H_ + h);
  float qv[4], kv[4], vv[4];
  float sq = 0.f, sk = 0.f;
#pragma unroll
  for (int dd = 0; dd < 4; ++dd) {
    int d = dg * 4 + dd;
    int oq = h * 32 + d;
    float q = conv3(rawb + (size_t)oq * S_, wdw + oq * 3, s);
    qv[dd] = q; sq += q * q;
    int ok = oq + 256;
    float k = conv3(rawb + (size_t)ok * S_, wdw + ok * 3, s);
    kv[dd] = k; sk += k * k;
    int ov = oq + 512;
    vv[dd] = conv3(rawb + (size_t)ov * S_, wdw + ov * 3, s);
  }
#pragma unroll
  for (int m = 1; m < 8; m <<= 1) {
    sq += __shfl_xor(sq, m);
    sk += __shfl_xor(sk, m);
  }
  float iq = tph / fmaxf(sqrtf(sq), 1e-12f);
  float ik = 1.f / fmaxf(sqrtf(sk), 1e-12f);
  size_t base = (bh * S_ + s) * 32 + dg * 4;

  float q0 = qv[0] * iq, q1 = qv[1] * iq, q2 = qv[2] * iq, q3 = qv[3] * iq;
  unsigned qh01 = cvt_pk_bf16(q0, q1), qh23 = cvt_pk_bf16(q2, q3);
  *(uint2v*)(q_hi + base) = uint2v{qh01, qh23};
  float ql0 = q0 - __uint_as_float(qh01 << 16);
  float ql1 = q1 - __uint_as_float(qh01 & 0xFFFF0000u);
  float ql2 = q2 - __uint_as_float(qh23 << 16);
  float ql3 = q3 - __uint_as_float(qh23 & 0xFFFF0000u);
  *(uint2v*)(q_lo + base) = uint2v{cvt_pk_bf16(ql0, ql1), cvt_pk_bf16(ql2, ql3)};

  float k0 = kv[0] * ik, k1 = kv[1] * ik, k2 = kv[2] * ik, k3 = kv[3] * ik;
  unsigned kh01 = cvt_pk_bf16(k0, k1), kh23 = cvt_pk_bf16(k2, k3);
  *(uint2v*)(k_hi + base) = uint2v{kh01, kh23};
  float kl0 = k0 - __uint_as_float(kh01 << 16);
  float kl1 = k1 - __uint_as_float(kh01 & 0xFFFF0000u);
  float kl2 = k2 - __uint_as_float(kh23 << 16);
  float kl3 = k3 - __uint_as_float(kh23 & 0xFFFF0000u);
  *(uint2v*)(k_lo + base) = uint2v{cvt_pk_bf16(kl0, kl1), cvt_pk_bf16(kl2, kl3)};

#pragma unroll
  for (int dd = 0; dd < 4; ++dd) {
    int d = dg * 4 + dd;
    vt[(bh * 32 + d) * S_ + s] = f2bf1(vv[dd]);
  }
}

// -------- per-row exact top-512 + softmax weights (in registers); vv -> exp weights --------
DEV float select_softmax_row(float (&vv)[32], int lane) {
  float vmax = vv[0], vmin = vv[0], sum = 0.f, sqs = 0.f;
#pragma unroll
  for (int j = 0; j < 32; ++j) {
    vmax = fmaxf(vmax, vv[j]); vmin = fminf(vmin, vv[j]);
    sum += vv[j]; sqs = fmaf(vv[j], vv[j], sqs);
  }
#pragma unroll
  for (int m = 1; m < 64; m <<= 1) {
    vmax = fmaxf(vmax, __shfl_xor(vmax, m));
    vmin = fminf(vmin, __shfl_xor(vmin, m));
    sum += __shfl_xor(sum, m);
    sqs += __shfl_xor(sqs, m);
  }
  float mu = sum * (1.f / 2048.f);
  float sig = sqrtf(fmaxf(sqs * (1.f / 2048.f) - mu * mu, 0.f));

  float vlo = vmin - 1e-3f, vhi = vmax;
  float flo = 1536.f, fhi = -512.f;
  int chi = 0;
  float T = vhi;
  bool exact = false;
  int lastside = 0;
  float piv = mu + 0.67449f * sig;
  if (!(piv > vlo && piv < vhi)) piv = 0.5f * (vlo + vhi);
  for (int it = 0; it < 32; ++it) {
    int c = 0;
#pragma unroll
    for (int j = 0; j < 32; ++j)
      c += (int)__popcll(__ballot(vv[j] > piv));
    if (c == TOPK) { T = piv; exact = true; break; }
    if (c > TOPK) {
      if (lastside == 1) fhi *= 0.5f;
      vlo = piv; flo = (float)(c - TOPK); lastside = 1;
    } else {
      if (lastside == -1) flo *= 0.5f;
      vhi = piv; fhi = (float)(c - TOPK); chi = c; lastside = -1;
    }
    float npiv;
    if (it == 0 && sig > 1e-20f) {
      float z = (piv - mu) / sig;
      float dens = 0.398942f * __expf(-0.5f * z * z) * (2048.f / sig);
      npiv = piv + (float)(c - TOPK) / fmaxf(dens, 1e-6f);
    } else {
      npiv = vhi - fhi * (vhi - vlo) / (fhi - flo);
    }
    if (!(npiv > vlo && npiv < vhi)) npiv = 0.5f * (vlo + vhi);
    if (!(npiv > vlo && npiv < vhi)) break;  // interval collapsed (ties)
    piv = npiv;
  }
  int cntGT = exact ? TOPK : chi;
  if (!exact) T = vhi;

  unsigned selbits = 0;
#pragma unroll
  for (int j = 0; j < 32; ++j)
    if (vv[j] > T) selbits |= (1u << j);
  int need = TOPK - cntGT;
  if (need > 0) {
    // ties broken by lowest col index (jax top_k order); j ascending == col ascending
    int base = 0;
    unsigned long long lmask = (lane == 0) ? 0ull : (~0ull >> (64 - lane));
#pragma unroll
    for (int j = 0; j < 32; ++j) {
      bool tie = (vv[j] == T);
      unsigned long long m = __ballot(tie);
      int rank = base + (int)__popcll(m & lmask);
      if (tie && rank < need) selbits |= (1u << j);
      base += (int)__popcll(m);
    }
  }

  float ssum = 0.f;
#pragma unroll
  for (int j = 0; j < 32; ++j) {
    float e = ((selbits >> j) & 1u) ? __expf(vv[j] - vmax) : 0.f;
    vv[j] = e;
    ssum += e;
  }
#pragma unroll
  for (int m = 1; m < 64; m <<= 1) ssum += __shfl_xor(ssum, m);
  return 1.f / ssum;
}

// ---------------- K3: fused QK^T (split-bf16) -> exact top-512 -> softmax -> PV ----------------
// 512 threads (8 waves), QT=16 rows; wave w owns rows 2w,2w+1. 33 KB LDS -> 4 WGs/CU (32 waves/CU).
// __launch_bounds__(512,4) -> 128 VGPR: v0[32]+v1[32] fit without spill (R8/R9 spilled at 64).
__global__ __launch_bounds__(512, 4) void k_attn(const unsigned short* __restrict__ q_hi,
                                                 const unsigned short* __restrict__ q_lo,
                                                 const unsigned short* __restrict__ k_hi,
                                                 const unsigned short* __restrict__ k_lo,
                                                 const unsigned short* __restrict__ vt,
                                                 unsigned short* __restrict__ ao) {
  extern __shared__ float smem[];
  __shared__ float is_arr[QT];                // per-row 1/ssum (deferred normalization)
  float* sc = smem;                           // [16][QSTR] fp32 quarter-scores
  unsigned short* P = (unsigned short*)smem;  // [16][PSTH] bf16 half-P (aliases sc), XOR-swizzled
  float* red = smem;                          // [8][529] partials (alias after P dead)
  int bid = blockIdx.x;
  int tile = bid & 127;                       // S/QT tiles per (b,h)
  int bh = bid >> 7;
  int q0 = tile * QT;
  int tid = threadIdx.x, lane = tid & 63, wv = tid >> 6;  // wv 0..7
  int l15 = lane & 15, lh = lane >> 4;
  const unsigned short* vb = vt + (size_t)bh * 32 * S_;

  // Q fragment: 16 distinct rows
  size_t qoff = ((size_t)bh * S_ + q0 + l15) * 32 + lh * 8;
  short8 ah = *(const short8*)(q_hi + qoff);
  short8 al = *(const short8*)(q_lo + qoff);
  size_t kbase = (size_t)bh * S_ * 32;

  float v0[32], v1[32];   // rows 2wv, 2wv+1; v[qq*8+jj] at col qq*512 + jj*64 + lane

  // ---- 4 quarter passes: compute 16x512 scores into sc, waves pull 2 rows to regs ----
#pragma unroll
  for (int qq = 0; qq < 4; ++qq) {
    int colg = qq * QCOLS + wv * 64;         // this wave's 64-col span
    const unsigned short* khp = k_hi + kbase + (size_t)(colg + l15) * 32 + lh * 8;
    const unsigned short* klp = k_lo + kbase + (size_t)(colg + l15) * 32 + lh * 8;
    short8 kh0 = *(const short8*)(khp);
    short8 kl0 = *(const short8*)(klp);
    short8 kh1 = *(const short8*)(khp + 512);
    short8 kl1 = *(const short8*)(klp + 512);
#pragma unroll
    for (int nt = 0; nt < 4; ++nt) {
      short8 kh2 = kh1, kl2 = kl1;
      if (nt < 2) {
        kh2 = *(const short8*)(khp + (nt + 2) * 512);
        kl2 = *(const short8*)(klp + (nt + 2) * 512);
      }
      f32x4 d = {};
      d = __builtin_amdgcn_mfma_f32_16x16x32_bf16(ah, kh0, d, 0, 0, 0);
      d = __builtin_amdgcn_mfma_f32_16x16x32_bf16(ah, kl0, d, 0, 0, 0);
      d = __builtin_amdgcn_mfma_f32_16x16x32_bf16(al, kh0, d, 0, 0, 0);
      int tloc = wv * 64 + nt * 16;
#pragma unroll
      for (int r = 0; r < 4; ++r)
        sc[(lh * 4 + r) * QSTR + tloc + l15] = d[r];
      kh0 = kh1; kl0 = kl1; kh1 = kh2; kl1 = kl2;
    }
    __syncthreads();  // quarter scores complete
#pragma unroll
    for (int jj = 0; jj < 8; ++jj) {
      v0[qq * 8 + jj] = sc[(2 * wv) * QSTR + jj * 64 + lane];
      v1[qq * 8 + jj] = sc[(2 * wv + 1) * QSTR + jj * 64 + lane];
    }
    __syncthreads();  // reads done; buffer reusable
  }

  // ---- selection + softmax weights for both rows (in registers) ----
  {
    float is0 = select_softmax_row(v0, lane);
    float is1 = select_softmax_row(v1, lane);
    if (lane == 0) { is_arr[2 * wv] = is0; is_arr[2 * wv + 1] = is1; }
  }

  // ---- P write (unnormalized exp) + PV per half; acc accumulates across halves ----
  // Swizzle: flat = (row*1024 + col) ^ (8*(row&7)) — bijective (rows 2048B-aligned).
  f32x4 acc0 = {}, acc1 = {};
  int swz_w0 = ((2 * wv) & 7) << 3;
  int swz_w1 = ((2 * wv + 1) & 7) << 3;
  int swz_r = (l15 & 7) << 3;
#pragma unroll
  for (int hhalf = 0; hhalf < 2; ++hhalf) {
#pragma unroll
    for (int j2 = 0; j2 < 16; ++j2) {
      int lc = (j2 >> 3) * QCOLS + (j2 & 7) * 64 + lane;  // local col in [0,1024)
      P[((2 * wv) * PSTH + lc) ^ swz_w0] = f2bf1(v0[hhalf * 16 + j2]);
      P[((2 * wv + 1) * PSTH + lc) ^ swz_w1] = f2bf1(v1[hhalf * 16 + j2]);
    }
    __syncthreads();  // half-P complete
    {
      const unsigned short* v0p = vb + (size_t)l15 * S_ + hhalf * HCOLS + wv * 128 + lh * 8;
      const unsigned short* v1p = v0p + 16 * S_;
#pragma unroll
      for (int kt = 0; kt < 4; ++kt) {
        int lc = wv * 128 + kt * 32 + lh * 8;
        short8 a = *(const short8*)(P + ((l15 * PSTH + lc) ^ swz_r));
        short8 b0 = *(const short8*)(v0p + kt * 32);
        short8 b1 = *(const short8*)(v1p + kt * 32);
        acc0 = __builtin_amdgcn_mfma_f32_16x16x32_bf16(a, b0, acc0, 0, 0, 0);
        acc1 = __builtin_amdgcn_mfma_f32_16x16x32_bf16(a, b1, acc1, 0, 0, 0);
      }
    }
    __syncthreads();  // PV reads done; buffer reusable
  }

  // ---- cross-wave reduction of 8 partial out(16x32) tiles ----
#pragma unroll
  for (int r = 0; r < 4; ++r) {
    red[wv * 529 + (lh * 4 + r) * 33 + l15] = acc0[r];
    red[wv * 529 + (lh * 4 + r) * 33 + 16 + l15] = acc1[r];
  }
  __syncthreads();
  {
    int row = tid >> 5, d = tid & 31;   // 512 threads = 16 rows x 32 d
    float s = 0.f;
#pragma unroll
    for (int w = 0; w < 8; ++w) s += red[w * 529 + row * 33 + d];
    s *= is_arr[row];
    ao[((size_t)bh * S_ + q0 + row) * 32 + d] = f2bf1(s);
  }
}

// ---------------- K4: output projection ----------------
__global__ __launch_bounds__(256) void k_proj(const unsigned short* __restrict__ wbf,
                                              const unsigned short* __restrict__ ao,
                                              float* __restrict__ out) {
  int b = blockIdx.z;
  int m0 = blockIdx.y * 64, n0 = blockIdx.x * 64;
  int tid = threadIdx.x, lane = tid & 63, wid = tid >> 6;
  int l15 = lane & 15, lh = lane >> 4;
  int wm = (wid >> 1) * 32, wn = (wid & 1) * 32;
  const unsigned short* aob = ao + (size_t)b * H_ * S_ * 32;
  f32x4 acc[2][2] = {};
  int mA = m0 + wm + l15;
  int nB = n0 + wn + l15;
  for (int k0 = 0; k0 < C_; k0 += 32) {
    int kk = k0 + lh * 8;
    int hh = kk >> 5;
    int dd = kk & 31;
    short8 a0 = *(const short8*)(wbf + (size_t)mA * C_ + kk);
    short8 a1 = *(const short8*)(wbf + (size_t)(mA + 16) * C_ + kk);
    short8 b0 = *(const short8*)(aob + ((size_t)hh * S_ + nB) * 32 + dd);
    short8 b1 = *(const short8*)(aob + ((size_t)hh * S_ + nB + 16) * 32 + dd);
    acc[0][0] = __builtin_amdgcn_mfma_f32_16x16x32_bf16(a0, b0, acc[0][0], 0, 0, 0);
    acc[0][1] = __builtin_amdgcn_mfma_f32_16x16x32_bf16(a0, b1, acc[0][1], 0, 0, 0);
    acc[1][0] = __builtin_amdgcn_mfma_f32_16x16x32_bf16(a1, b0, acc[1][0], 0, 0, 0);
    acc[1][1] = __builtin_amdgcn_mfma_f32_16x16x32_bf16(a1, b1, acc[1][1], 0, 0, 0);
  }
  float* ob = out + (size_t)b * C_ * S_;
#pragma unroll
  for (int i = 0; i < 2; ++i)
#pragma unroll
    for (int j = 0; j < 2; ++j)
#pragma unroll
      for (int r = 0; r < 4; ++r) {
        int row = m0 + wm + i * 16 + lh * 4 + r;
        int col = n0 + wn + j * 16 + l15;
        ob[(size_t)row * S_ + col] = acc[i][j][r];
      }
}

extern "C" void kernel_launch(void* const* d_in, const int* in_sizes, int n_in,
                              void* d_out, int out_size, void* d_ws, size_t ws_size,
                              hipStream_t stream) {
  const float* x = (const float*)d_in[0];
  const float* wqkv = (const float*)d_in[1];
  const float* wdw = (const float*)d_in[2];
  const float* wproj = (const float*)d_in[3];
  const float* temp = (const float*)d_in[4];
  float* out = (float*)d_out;

  char* ws = (char*)d_ws;
  size_t off = 0;
  auto alloc = [&](size_t bytes) -> void* {
    void* p = ws + off;
    off += (bytes + 255) & ~(size_t)255;
    return p;
  };
  unsigned short* x_hi     = (unsigned short*)alloc((size_t)B_ * S_ * C_ * 2);
  unsigned short* x_lo     = (unsigned short*)alloc((size_t)B_ * S_ * C_ * 2);
  unsigned short* wq_hi    = (unsigned short*)alloc((size_t)O3_ * C_ * 2);
  unsigned short* wq_lo    = (unsigned short*)alloc((size_t)O3_ * C_ * 2);
  unsigned short* wproj_bf = (unsigned short*)alloc((size_t)C_ * C_ * 2);
  float*          raw      = (float*)alloc((size_t)B_ * O3_ * S_ * 4);
  unsigned short* k_hi     = (unsigned short*)alloc((size_t)B_ * H_ * S_ * 32 * 2);
  unsigned short* k_lo     = (unsigned short*)alloc((size_t)B_ * H_ * S_ * 32 * 2);
  unsigned short* vt       = (unsigned short*)alloc((size_t)B_ * H_ * 32 * S_ * 2);
  unsigned short* q_hi     = x_hi;                 // alias (x dead after k_qkv)
  unsigned short* q_lo     = x_lo;                 // alias
  unsigned short* ao       = (unsigned short*)raw; // alias (raw dead after k_dwnorm)

  (void)hipFuncSetAttribute(reinterpret_cast<const void*>(k_attn),
                            hipFuncAttributeMaxDynamicSharedMemorySize, (int)K3_LDS_BYTES);

  k_convw<<<dim3((O3_ * C_ + 255) / 256), dim3(256), 0, stream>>>(wqkv, wproj, wq_hi, wq_lo, wproj_bf);
  k_xt<<<dim3(S_ / 32, C_ / 32, B_), dim3(32, 8), 0, stream>>>(x, x_hi, x_lo);
  k_qkv<<<dim3(S_ / 64, O3_ / 64, B_), dim3(256), 0, stream>>>(wq_hi, wq_lo, x_hi, x_lo, raw);
  k_dwnorm<<<dim3(S_ / 32, H_, B_), dim3(256), 0, stream>>>(raw, wdw, temp, q_hi, q_lo, k_hi, k_lo, vt);
  k_attn<<<dim3(B_ * H_ * (S_ / QT)), dim3(512), K3_LDS_BYTES, stream>>>(q_hi, q_lo, k_hi, k_lo, vt, ao);
  k_proj<<<dim3(S_ / 64, C_ / 64, B_), dim3(256), 0, stream>>>(wproj_bf, ao, out);
}

// Round 11
// 275.265 us; speedup vs baseline: 1.1130x; 1.1130x over previous
//
#include <hip/hip_runtime.h>
#include <math.h>

typedef __attribute__((ext_vector_type(8))) short short8;
typedef __attribute__((ext_vector_type(4))) float f32x4;
typedef __attribute__((ext_vector_type(2))) unsigned int uint2v;

#define DEV __device__ __forceinline__

static constexpr int B_ = 4, C_ = 256, S_ = 2048, H_ = 8, O3_ = 768;
static constexpr int TOPK = 512;
static constexpr int QT = 16;           // q rows per workgroup in attention
static constexpr int QCOLS = 512;       // score cols per quarter pass
static constexpr int QSTR = 516;        // fp32 score row stride (quarter buffer)
static constexpr int QBUF = 16 * QSTR;  // floats per quarter buffer (8256)
static constexpr int PSTH = 1024;       // bf16 P half row stride
static constexpr int P1OFF = 2 * QBUF;  // ushort offset of P1 = 16512 (64-aligned -> swizzle bijective)
// LDS: 2 quarter buffers = 66048 B. P0 (32768 B) aliases buf region at 0; P1 at byte 33024.
// red (16*529*4 = 33856 B) aliases after PV. -> 2 WGs/CU (1024 thr, 16 waves), 32 waves/CU.
static constexpr size_t K3_LDS_BYTES = (size_t)2 * QBUF * 4;  // 66048 B

DEV unsigned cvt_pk_bf16(float a, float b) {
  unsigned r;
  asm("v_cvt_pk_bf16_f32 %0, %1, %2" : "=v"(r) : "v"(a), "v"(b));
  return r;  // lo16 = bf16(a), hi16 = bf16(b)
}
DEV unsigned short f2bf1(float f) { return (unsigned short)(cvt_pk_bf16(f, f) & 0xFFFFu); }
DEV float bf2f(unsigned short h) { return __uint_as_float(((unsigned)h) << 16); }
DEV void hilo(float f, unsigned short& h, unsigned short& l) {
  unsigned p = cvt_pk_bf16(f, f);
  h = (unsigned short)p;
  float r = f - __uint_as_float(p << 16);
  l = (unsigned short)(cvt_pk_bf16(r, r) & 0xFFFFu);
}

// ---------------- K0a: weights -> bf16 hi/lo (qkv), bf16 (proj) ----------------
__global__ void k_convw(const float* __restrict__ wqkv, const float* __restrict__ wproj,
                        unsigned short* __restrict__ wq_hi, unsigned short* __restrict__ wq_lo,
                        unsigned short* __restrict__ wproj_bf) {
  int i = blockIdx.x * 256 + threadIdx.x;
  if (i < O3_ * C_) {
    unsigned short h, l;
    hilo(wqkv[i], h, l);
    wq_hi[i] = h;
    wq_lo[i] = l;
  }
  if (i < C_ * C_) wproj_bf[i] = f2bf1(wproj[i]);
}

// ---------------- K0b: transpose x [b][c][s] -> xT hi/lo bf16 [b][s][c] ----------------
__global__ void k_xt(const float* __restrict__ x, unsigned short* __restrict__ xT_hi,
                     unsigned short* __restrict__ xT_lo) {
  __shared__ float t[32][33];
  int b = blockIdx.z;
  int c0 = blockIdx.y * 32, s0 = blockIdx.x * 32;
  int tx = threadIdx.x, ty = threadIdx.y;
  const float* xb = x + (size_t)b * C_ * S_;
#pragma unroll
  for (int j = 0; j < 4; ++j)
    t[ty + 8 * j][tx] = xb[(size_t)(c0 + ty + 8 * j) * S_ + s0 + tx];
  __syncthreads();
  unsigned short* hb = xT_hi + (size_t)b * S_ * C_;
  unsigned short* lb = xT_lo + (size_t)b * S_ * C_;
#pragma unroll
  for (int j = 0; j < 4; ++j) {
    unsigned short h, l;
    hilo(t[tx][ty + 8 * j], h, l);
    size_t o = (size_t)(s0 + ty + 8 * j) * C_ + c0 + tx;
    hb[o] = h;
    lb[o] = l;
  }
}

// ---------------- K1: qkv_raw = W_qkv @ x  (split-bf16 3-pass MFMA, ~fp32 accurate) ----------------
__global__ __launch_bounds__(256) void k_qkv(const unsigned short* __restrict__ w_hi,
                                             const unsigned short* __restrict__ w_lo,
                                             const unsigned short* __restrict__ x_hi,
                                             const unsigned short* __restrict__ x_lo,
                                             float* __restrict__ raw) {
  int b = blockIdx.z;
  int m0 = blockIdx.y * 64, n0 = blockIdx.x * 64;
  int tid = threadIdx.x, lane = tid & 63, wid = tid >> 6;
  int l15 = lane & 15, lh = lane >> 4;
  int wm = (wid >> 1) * 32, wn = (wid & 1) * 32;
  const unsigned short* xhb = x_hi + (size_t)b * S_ * C_;
  const unsigned short* xlb = x_lo + (size_t)b * S_ * C_;
  f32x4 acc[2][2] = {};
  int mA = m0 + wm + l15;
  int nB = n0 + wn + l15;
  for (int k0 = 0; k0 < C_; k0 += 32) {
    int kk = k0 + lh * 8;
    short8 a0h = *(const short8*)(w_hi + (size_t)mA * C_ + kk);
    short8 a1h = *(const short8*)(w_hi + (size_t)(mA + 16) * C_ + kk);
    short8 a0l = *(const short8*)(w_lo + (size_t)mA * C_ + kk);
    short8 a1l = *(const short8*)(w_lo + (size_t)(mA + 16) * C_ + kk);
    short8 b0h = *(const short8*)(xhb + (size_t)nB * C_ + kk);
    short8 b1h = *(const short8*)(xhb + (size_t)(nB + 16) * C_ + kk);
    short8 b0l = *(const short8*)(xlb + (size_t)nB * C_ + kk);
    short8 b1l = *(const short8*)(xlb + (size_t)(nB + 16) * C_ + kk);
    acc[0][0] = __builtin_amdgcn_mfma_f32_16x16x32_bf16(a0h, b0h, acc[0][0], 0, 0, 0);
    acc[0][1] = __builtin_amdgcn_mfma_f32_16x16x32_bf16(a0h, b1h, acc[0][1], 0, 0, 0);
    acc[1][0] = __builtin_amdgcn_mfma_f32_16x16x32_bf16(a1h, b0h, acc[1][0], 0, 0, 0);
    acc[1][1] = __builtin_amdgcn_mfma_f32_16x16x32_bf16(a1h, b1h, acc[1][1], 0, 0, 0);
    acc[0][0] = __builtin_amdgcn_mfma_f32_16x16x32_bf16(a0h, b0l, acc[0][0], 0, 0, 0);
    acc[0][1] = __builtin_amdgcn_mfma_f32_16x16x32_bf16(a0h, b1l, acc[0][1], 0, 0, 0);
    acc[1][0] = __builtin_amdgcn_mfma_f32_16x16x32_bf16(a1h, b0l, acc[1][0], 0, 0, 0);
    acc[1][1] = __builtin_amdgcn_mfma_f32_16x16x32_bf16(a1h, b1l, acc[1][1], 0, 0, 0);
    acc[0][0] = __builtin_amdgcn_mfma_f32_16x16x32_bf16(a0l, b0h, acc[0][0], 0, 0, 0);
    acc[0][1] = __builtin_amdgcn_mfma_f32_16x16x32_bf16(a0l, b1h, acc[0][1], 0, 0, 0);
    acc[1][0] = __builtin_amdgcn_mfma_f32_16x16x32_bf16(a1l, b0h, acc[1][0], 0, 0, 0);
    acc[1][1] = __builtin_amdgcn_mfma_f32_16x16x32_bf16(a1l, b1h, acc[1][1], 0, 0, 0);
  }
  float* rawb = raw + (size_t)b * O3_ * S_;
#pragma unroll
  for (int i = 0; i < 2; ++i)
#pragma unroll
    for (int j = 0; j < 2; ++j)
#pragma unroll
      for (int r = 0; r < 4; ++r) {
        int row = m0 + wm + i * 16 + lh * 4 + r;
        int col = n0 + wn + j * 16 + l15;
        rawb[(size_t)row * S_ + col] = acc[i][j][r];
      }
}

// ---------------- K2: depthwise conv + head split + l2norm (+temperature fold) ----------------
DEV float conv3(const float* __restrict__ rp, const float* __restrict__ w, int s) {
  float a = (s > 0) ? rp[s - 1] : 0.f;
  float b = rp[s];
  float c = (s < S_ - 1) ? rp[s + 1] : 0.f;
  return w[0] * a + w[1] * b + w[2] * c;
}

__global__ __launch_bounds__(256) void k_dwnorm(const float* __restrict__ raw,
                                                const float* __restrict__ wdw,
                                                const float* __restrict__ temp,
                                                unsigned short* __restrict__ q_hi,
                                                unsigned short* __restrict__ q_lo,
                                                unsigned short* __restrict__ k_hi,
                                                unsigned short* __restrict__ k_lo,
                                                unsigned short* __restrict__ vt) {
  int b = blockIdx.z, h = blockIdx.y;
  int tid = threadIdx.x;
  int wave = tid >> 6, lane = tid & 63;
  int dg = lane & 7;
  int sl = lane >> 3;
  int s = blockIdx.x * 32 + wave * 8 + sl;
  const float* rawb = raw + (size_t)b * O3_ * S_;
  float tph = temp[h];
  size_t bh = (size_t)(b * H_ + h);
  float qv[4], kv[4], vv[4];
  float sq = 0.f, sk = 0.f;
#pragma unroll
  for (int dd = 0; dd < 4; ++dd) {
    int d = dg * 4 + dd;
    int oq = h * 32 + d;
    float q = conv3(rawb + (size_t)oq * S_, wdw + oq * 3, s);
    qv[dd] = q; sq += q * q;
    int ok = oq + 256;
    float k = conv3(rawb + (size_t)ok * S_, wdw + ok * 3, s);
    kv[dd] = k; sk += k * k;
    int ov = oq + 512;
    vv[dd] = conv3(rawb + (size_t)ov * S_, wdw + ov * 3, s);
  }
#pragma unroll
  for (int m = 1; m < 8; m <<= 1) {
    sq += __shfl_xor(sq, m);
    sk += __shfl_xor(sk, m);
  }
  float iq = tph / fmaxf(sqrtf(sq), 1e-12f);
  float ik = 1.f / fmaxf(sqrtf(sk), 1e-12f);
  size_t base = (bh * S_ + s) * 32 + dg * 4;

  float q0 = qv[0] * iq, q1 = qv[1] * iq, q2 = qv[2] * iq, q3 = qv[3] * iq;
  unsigned qh01 = cvt_pk_bf16(q0, q1), qh23 = cvt_pk_bf16(q2, q3);
  *(uint2v*)(q_hi + base) = uint2v{qh01, qh23};
  float ql0 = q0 - __uint_as_float(qh01 << 16);
  float ql1 = q1 - __uint_as_float(qh01 & 0xFFFF0000u);
  float ql2 = q2 - __uint_as_float(qh23 << 16);
  float ql3 = q3 - __uint_as_float(qh23 & 0xFFFF0000u);
  *(uint2v*)(q_lo + base) = uint2v{cvt_pk_bf16(ql0, ql1), cvt_pk_bf16(ql2, ql3)};

  float k0 = kv[0] * ik, k1 = kv[1] * ik, k2 = kv[2] * ik, k3 = kv[3] * ik;
  unsigned kh01 = cvt_pk_bf16(k0, k1), kh23 = cvt_pk_bf16(k2, k3);
  *(uint2v*)(k_hi + base) = uint2v{kh01, kh23};
  float kl0 = k0 - __uint_as_float(kh01 << 16);
  float kl1 = k1 - __uint_as_float(kh01 & 0xFFFF0000u);
  float kl2 = k2 - __uint_as_float(kh23 << 16);
  float kl3 = k3 - __uint_as_float(kh23 & 0xFFFF0000u);
  *(uint2v*)(k_lo + base) = uint2v{cvt_pk_bf16(kl0, kl1), cvt_pk_bf16(kl2, kl3)};

#pragma unroll
  for (int dd = 0; dd < 4; ++dd) {
    int d = dg * 4 + dd;
    vt[(bh * 32 + d) * S_ + s] = f2bf1(vv[dd]);
  }
}

// ---------------- K3: fused QK^T (split-bf16) -> exact top-512 -> softmax -> PV ----------------
// 1024 thr (16 waves), QT=16; wave w owns row w. 66 KB LDS -> 2 WGs/CU (32 waves/CU).
// Pipelined quarter-staging (double score buffer) + double half-P buffers: 8 barriers (was 10).
__global__ __launch_bounds__(1024, 8) void k_attn(const unsigned short* __restrict__ q_hi,
                                                  const unsigned short* __restrict__ q_lo,
                                                  const unsigned short* __restrict__ k_hi,
                                                  const unsigned short* __restrict__ k_lo,
                                                  const unsigned short* __restrict__ vt,
                                                  unsigned short* __restrict__ ao) {
  extern __shared__ float smem[];
  __shared__ float is_arr[QT];
  unsigned short* Pb = (unsigned short*)smem;   // P0 at ushort 0, P1 at ushort P1OFF
  float* red = smem;                            // [16][529] partials (alias, after PV done)
  int bid = blockIdx.x;
  int tile = bid & 127;
  int bh = bid >> 7;
  int q0 = tile * QT;
  int tid = threadIdx.x, lane = tid & 63, wv = tid >> 6;  // wv 0..15
  int l15 = lane & 15, lh = lane >> 4;
  const unsigned short* vb = vt + (size_t)bh * 32 * S_;

  size_t qoff = ((size_t)bh * S_ + q0 + l15) * 32 + lh * 8;
  short8 ah = *(const short8*)(q_hi + qoff);
  short8 al = *(const short8*)(q_lo + qoff);
  size_t kbase = (size_t)bh * S_ * 32;

  float v[32];

  // ---- pipelined quarter staging: stage q(n) -> barrier -> {extract q(n) || stage q(n+1)} ----
  // wave wv covers cols qq*512 + wv*32 + [0,32): 2 MFMA-tiles x 3 passes.
  short8 kh0, kl0, kh1, kl1;
  {
    const unsigned short* kp = k_hi + kbase + (size_t)(wv * 32 + l15) * 32 + lh * 8;
    const unsigned short* lp = k_lo + kbase + (size_t)(wv * 32 + l15) * 32 + lh * 8;
    kh0 = *(const short8*)(kp);       kl0 = *(const short8*)(lp);
    kh1 = *(const short8*)(kp + 512); kl1 = *(const short8*)(lp + 512);
  }
#pragma unroll
  for (int qq = 0; qq < 4; ++qq) {
    float* buf = smem + (qq & 1) * QBUF;
    {
      f32x4 d0 = {}, d1 = {};
      d0 = __builtin_amdgcn_mfma_f32_16x16x32_bf16(ah, kh0, d0, 0, 0, 0);
      d0 = __builtin_amdgcn_mfma_f32_16x16x32_bf16(ah, kl0, d0, 0, 0, 0);
      d0 = __builtin_amdgcn_mfma_f32_16x16x32_bf16(al, kh0, d0, 0, 0, 0);
      d1 = __builtin_amdgcn_mfma_f32_16x16x32_bf16(ah, kh1, d1, 0, 0, 0);
      d1 = __builtin_amdgcn_mfma_f32_16x16x32_bf16(ah, kl1, d1, 0, 0, 0);
      d1 = __builtin_amdgcn_mfma_f32_16x16x32_bf16(al, kh1, d1, 0, 0, 0);
      int tloc = wv * 32 + l15;
#pragma unroll
      for (int r = 0; r < 4; ++r) {
        buf[(lh * 4 + r) * QSTR + tloc] = d0[r];
        buf[(lh * 4 + r) * QSTR + tloc + 16] = d1[r];
      }
      if (qq < 3) {  // prefetch next quarter's K frags (regs now free)
        int colg = (qq + 1) * QCOLS + wv * 32;
        const unsigned short* kp = k_hi + kbase + (size_t)(colg + l15) * 32 + lh * 8;
        const unsigned short* lp = k_lo + kbase + (size_t)(colg + l15) * 32 + lh * 8;
        kh0 = *(const short8*)(kp);       kl0 = *(const short8*)(lp);
        kh1 = *(const short8*)(kp + 512); kl1 = *(const short8*)(lp + 512);
      }
    }
    __syncthreads();  // buf(qq&1) complete; previous buffer's reads also fenced
#pragma unroll
    for (int jj = 0; jj < 8; ++jj)
      v[qq * 8 + jj] = buf[wv * QSTR + jj * 64 + lane];
    // no second barrier: next iteration writes the OTHER buffer; the write-back to THIS
    // buffer happens in iteration qq+2, after barrier qq+1 which fences these reads.
  }

  // ---- selection (exact top-512) + softmax weights, in registers ----
  // col of v[j]: t = (j>>3)*512 + (j&7)*64 + lane (ascending j-major -> tie order ok)
  {
    float vmax = v[0], vmin = v[0], sum = 0.f, sqs = 0.f;
#pragma unroll
    for (int j = 0; j < 32; ++j) {
      vmax = fmaxf(vmax, v[j]); vmin = fminf(vmin, v[j]);
      sum += v[j]; sqs = fmaf(v[j], v[j], sqs);
    }
#pragma unroll
    for (int m = 1; m < 64; m <<= 1) {
      vmax = fmaxf(vmax, __shfl_xor(vmax, m));
      vmin = fminf(vmin, __shfl_xor(vmin, m));
      sum += __shfl_xor(sum, m);
      sqs += __shfl_xor(sqs, m);
    }
    float mu = sum * (1.f / 2048.f);
    float sig = sqrtf(fmaxf(sqs * (1.f / 2048.f) - mu * mu, 0.f));

    float vlo = vmin - 1e-3f, vhi = vmax;
    float flo = 1536.f, fhi = -512.f;
    int chi = 0;
    float T = vhi;
    bool exact = false;
    int lastside = 0;
    float piv = mu + 0.67449f * sig;
    if (!(piv > vlo && piv < vhi)) piv = 0.5f * (vlo + vhi);
    for (int it = 0; it < 32; ++it) {
      int c = 0;
#pragma unroll
      for (int j = 0; j < 32; ++j)
        c += (int)__popcll(__ballot(v[j] > piv));
      if (c == TOPK) { T = piv; exact = true; break; }
      if (c > TOPK) {
        if (lastside == 1) fhi *= 0.5f;
        vlo = piv; flo = (float)(c - TOPK); lastside = 1;
      } else {
        if (lastside == -1) flo *= 0.5f;
        vhi = piv; fhi = (float)(c - TOPK); chi = c; lastside = -1;
      }
      float npiv;
      if (it == 0 && sig > 1e-20f) {
        float z = (piv - mu) / sig;
        float dens = 0.398942f * __expf(-0.5f * z * z) * (2048.f / sig);
        npiv = piv + (float)(c - TOPK) / fmaxf(dens, 1e-6f);
      } else {
        npiv = vhi - fhi * (vhi - vlo) / (fhi - flo);
      }
      if (!(npiv > vlo && npiv < vhi)) npiv = 0.5f * (vlo + vhi);
      if (!(npiv > vlo && npiv < vhi)) break;
      piv = npiv;
    }
    int cntGT = exact ? TOPK : chi;
    if (!exact) T = vhi;

    unsigned selbits = 0;
#pragma unroll
    for (int j = 0; j < 32; ++j)
      if (v[j] > T) selbits |= (1u << j);
    int need = TOPK - cntGT;
    if (need > 0) {
      int base = 0;
      unsigned long long lmask = (lane == 0) ? 0ull : (~0ull >> (64 - lane));
#pragma unroll
      for (int j = 0; j < 32; ++j) {
        bool tie = (v[j] == T);
        unsigned long long m = __ballot(tie);
        int rank = base + (int)__popcll(m & lmask);
        if (tie && rank < need) selbits |= (1u << j);
        base += (int)__popcll(m);
      }
    }

    float ssum = 0.f;
#pragma unroll
    for (int j = 0; j < 32; ++j) {
      float e = ((selbits >> j) & 1u) ? __expf(v[j] - vmax) : 0.f;
      v[j] = e;
      ssum += e;
    }
#pragma unroll
    for (int m = 1; m < 64; m <<= 1) ssum += __shfl_xor(ssum, m);
    if (lane == 0) is_arr[wv] = 1.f / ssum;
  }

  // ---- P0 write; bar; {PV0 || P1 write}; bar; PV1 ----
  // Swizzle: idx = (base + row*1024 + col) ^ (8*(row&7)); bases 64-ushort aligned -> bijective.
  // half h covers global cols [h*1024, h*1024+1024) = quarters 2h, 2h+1;
  // v[j] for half h: j in [h*16, h*16+16), local col = (j>>3 & 1)*512 + (j&7)*64 + lane.
  f32x4 acc0 = {}, acc1 = {};
  int swz_w = (wv & 7) << 3;
  int swz_r = (l15 & 7) << 3;
#pragma unroll
  for (int j2 = 0; j2 < 16; ++j2) {   // P0: v[0..15]
    int lc = ((j2 >> 3) & 1) * 512 + (j2 & 7) * 64 + lane;
    Pb[(wv * PSTH + lc) ^ swz_w] = f2bf1(v[j2]);
  }
  __syncthreads();  // P0 ready
  {
    // P1 write (independent of PV0; fills barrier-to-barrier span)
#pragma unroll
    for (int j2 = 0; j2 < 16; ++j2) {
      int lc = ((j2 >> 3) & 1) * 512 + (j2 & 7) * 64 + lane;
      Pb[P1OFF + ((wv * PSTH + lc) ^ swz_w)] = f2bf1(v[16 + j2]);
    }
    // PV0
    const unsigned short* v0p = vb + (size_t)l15 * S_ + wv * 64 + lh * 8;
    const unsigned short* v1p = v0p + 16 * S_;
#pragma unroll
    for (int kt = 0; kt < 2; ++kt) {
      int lc = wv * 64 + kt * 32 + lh * 8;
      short8 a = *(const short8*)(Pb + ((l15 * PSTH + lc) ^ swz_r));
      short8 b0 = *(const short8*)(v0p + kt * 32);
      short8 b1 = *(const short8*)(v1p + kt * 32);
      acc0 = __builtin_amdgcn_mfma_f32_16x16x32_bf16(a, b0, acc0, 0, 0, 0);
      acc1 = __builtin_amdgcn_mfma_f32_16x16x32_bf16(a, b1, acc1, 0, 0, 0);
    }
  }
  __syncthreads();  // P1 ready (and PV0 reads of P0 done)
  {
    const unsigned short* v0p = vb + (size_t)l15 * S_ + 1024 + wv * 64 + lh * 8;
    const unsigned short* v1p = v0p + 16 * S_;
#pragma unroll
    for (int kt = 0; kt < 2; ++kt) {
      int lc = wv * 64 + kt * 32 + lh * 8;
      short8 a = *(const short8*)(Pb + P1OFF + ((l15 * PSTH + lc) ^ swz_r));
      short8 b0 = *(const short8*)(v0p + kt * 32);
      short8 b1 = *(const short8*)(v1p + kt * 32);
      acc0 = __builtin_amdgcn_mfma_f32_16x16x32_bf16(a, b0, acc0, 0, 0, 0);
      acc1 = __builtin_amdgcn_mfma_f32_16x16x32_bf16(a, b1, acc1, 0, 0, 0);
    }
  }
  __syncthreads();  // PV1 reads done; red region (aliases P) safe

  // ---- cross-wave reduction of 16 partial out(16x32) tiles ----
#pragma unroll
  for (int r = 0; r < 4; ++r) {
    red[wv * 529 + (lh * 4 + r) * 33 + l15] = acc0[r];
    red[wv * 529 + (lh * 4 + r) * 33 + 16 + l15] = acc1[r];
  }
  __syncthreads();
  if (tid < 512) {
    int row = tid >> 5, d = tid & 31;
    float s = 0.f;
#pragma unroll
    for (int w = 0; w < 16; ++w) s += red[w * 529 + row * 33 + d];
    s *= is_arr[row];
    ao[((size_t)bh * S_ + q0 + row) * 32 + d] = f2bf1(s);
  }
}

// ---------------- K4: output projection ----------------
__global__ __launch_bounds__(256) void k_proj(const unsigned short* __restrict__ wbf,
                                              const unsigned short* __restrict__ ao,
                                              float* __restrict__ out) {
  int b = blockIdx.z;
  int m0 = blockIdx.y * 64, n0 = blockIdx.x * 64;
  int tid = threadIdx.x, lane = tid & 63, wid = tid >> 6;
  int l15 = lane & 15, lh = lane >> 4;
  int wm = (wid >> 1) * 32, wn = (wid & 1) * 32;
  const unsigned short* aob = ao + (size_t)b * H_ * S_ * 32;
  f32x4 acc[2][2] = {};
  int mA = m0 + wm + l15;
  int nB = n0 + wn + l15;
  for (int k0 = 0; k0 < C_; k0 += 32) {
    int kk = k0 + lh * 8;
    int hh = kk >> 5;
    int dd = kk & 31;
    short8 a0 = *(const short8*)(wbf + (size_t)mA * C_ + kk);
    short8 a1 = *(const short8*)(wbf + (size_t)(mA + 16) * C_ + kk);
    short8 b0 = *(const short8*)(aob + ((size_t)hh * S_ + nB) * 32 + dd);
    short8 b1 = *(const short8*)(aob + ((size_t)hh * S_ + nB + 16) * 32 + dd);
    acc[0][0] = __builtin_amdgcn_mfma_f32_16x16x32_bf16(a0, b0, acc[0][0], 0, 0, 0);
    acc[0][1] = __builtin_amdgcn_mfma_f32_16x16x32_bf16(a0, b1, acc[0][1], 0, 0, 0);
    acc[1][0] = __builtin_amdgcn_mfma_f32_16x16x32_bf16(a1, b0, acc[1][0], 0, 0, 0);
    acc[1][1] = __builtin_amdgcn_mfma_f32_16x16x32_bf16(a1, b1, acc[1][1], 0, 0, 0);
  }
  float* ob = out + (size_t)b * C_ * S_;
#pragma unroll
  for (int i = 0; i < 2; ++i)
#pragma unroll
    for (int j = 0; j < 2; ++j)
#pragma unroll
      for (int r = 0; r < 4; ++r) {
        int row = m0 + wm + i * 16 + lh * 4 + r;
        int col = n0 + wn + j * 16 + l15;
        ob[(size_t)row * S_ + col] = acc[i][j][r];
      }
}

extern "C" void kernel_launch(void* const* d_in, const int* in_sizes, int n_in,
                              void* d_out, int out_size, void* d_ws, size_t ws_size,
                              hipStream_t stream) {
  const float* x = (const float*)d_in[0];
  const float* wqkv = (const float*)d_in[1];
  const float* wdw = (const float*)d_in[2];
  const float* wproj = (const float*)d_in[3];
  const float* temp = (const float*)d_in[4];
  float* out = (float*)d_out;

  char* ws = (char*)d_ws;
  size_t off = 0;
  auto alloc = [&](size_t bytes) -> void* {
    void* p = ws + off;
    off += (bytes + 255) & ~(size_t)255;
    return p;
  };
  unsigned short* x_hi     = (unsigned short*)alloc((size_t)B_ * S_ * C_ * 2);
  unsigned short* x_lo     = (unsigned short*)alloc((size_t)B_ * S_ * C_ * 2);
  unsigned short* wq_hi    = (unsigned short*)alloc((size_t)O3_ * C_ * 2);
  unsigned short* wq_lo    = (unsigned short*)alloc((size_t)O3_ * C_ * 2);
  unsigned short* wproj_bf = (unsigned short*)alloc((size_t)C_ * C_ * 2);
  float*          raw      = (float*)alloc((size_t)B_ * O3_ * S_ * 4);
  unsigned short* k_hi     = (unsigned short*)alloc((size_t)B_ * H_ * S_ * 32 * 2);
  unsigned short* k_lo     = (unsigned short*)alloc((size_t)B_ * H_ * S_ * 32 * 2);
  unsigned short* vt       = (unsigned short*)alloc((size_t)B_ * H_ * 32 * S_ * 2);
  unsigned short* q_hi     = x_hi;                 // alias (x dead after k_qkv)
  unsigned short* q_lo     = x_lo;                 // alias
  unsigned short* ao       = (unsigned short*)raw; // alias (raw dead after k_dwnorm)

  (void)hipFuncSetAttribute(reinterpret_cast<const void*>(k_attn),
                            hipFuncAttributeMaxDynamicSharedMemorySize, (int)K3_LDS_BYTES);

  k_convw<<<dim3((O3_ * C_ + 255) / 256), dim3(256), 0, stream>>>(wqkv, wproj, wq_hi, wq_lo, wproj_bf);
  k_xt<<<dim3(S_ / 32, C_ / 32, B_), dim3(32, 8), 0, stream>>>(x, x_hi, x_lo);
  k_qkv<<<dim3(S_ / 64, O3_ / 64, B_), dim3(256), 0, stream>>>(wq_hi, wq_lo, x_hi, x_lo, raw);
  k_dwnorm<<<dim3(S_ / 32, H_, B_), dim3(256), 0, stream>>>(raw, wdw, temp, q_hi, q_lo, k_hi, k_lo, vt);
  k_attn<<<dim3(B_ * H_ * (S_ / QT)), dim3(1024), K3_LDS_BYTES, stream>>>(q_hi, q_lo, k_hi, k_lo, vt, ao);
  k_proj<<<dim3(S_ / 64, C_ / 64, B_), dim3(256), 0, stream>>>(wproj_bf, ao, out);
}

// Round 12
// 273.144 us; speedup vs baseline: 1.1217x; 1.0078x over previous
//
#include <hip/hip_runtime.h>
#include <math.h>

typedef __attribute__((ext_vector_type(8))) short short8;
typedef __attribute__((ext_vector_type(4))) float f32x4;
typedef __attribute__((ext_vector_type(2))) float f32x2;
typedef __attribute__((ext_vector_type(2))) unsigned int uint2v;

#define DEV __device__ __forceinline__

static constexpr int B_ = 4, C_ = 256, S_ = 2048, H_ = 8, O3_ = 768;
static constexpr int TOPK = 512;
static constexpr int QT = 16;           // q rows per workgroup in attention
static constexpr int QCOLS = 512;       // score cols per quarter pass
static constexpr int QSTR = 516;        // fp32 score row stride (quarter buffer)
static constexpr int QBUF = 16 * QSTR;  // floats per quarter buffer (8256)
static constexpr int PSTH = 1024;       // bf16 P half row stride
static constexpr int P1OFF = 2 * QBUF;  // ushort offset of P1 = 16512 (64-aligned -> swizzle bijective)
// LDS: 2 quarter buffers = 66048 B. P0 (32768 B) aliases buf region at 0; P1 at byte 33024.
// red (16*529*4 = 33856 B) aliases after PV. -> 2 WGs/CU (1024 thr, 16 waves), 32 waves/CU.
static constexpr size_t K3_LDS_BYTES = (size_t)2 * QBUF * 4;  // 66048 B

DEV unsigned cvt_pk_bf16(float a, float b) {
  unsigned r;
  asm("v_cvt_pk_bf16_f32 %0, %1, %2" : "=v"(r) : "v"(a), "v"(b));
  return r;  // lo16 = bf16(a), hi16 = bf16(b)
}
DEV unsigned short f2bf1(float f) { return (unsigned short)(cvt_pk_bf16(f, f) & 0xFFFFu); }
DEV float bf2f(unsigned short h) { return __uint_as_float(((unsigned)h) << 16); }
DEV void hilo(float f, unsigned short& h, unsigned short& l) {
  unsigned p = cvt_pk_bf16(f, f);
  h = (unsigned short)p;
  float r = f - __uint_as_float(p << 16);
  l = (unsigned short)(cvt_pk_bf16(r, r) & 0xFFFFu);
}

// ---------------- K0a: weights -> bf16 hi/lo (qkv), bf16 (proj) ----------------
__global__ void k_convw(const float* __restrict__ wqkv, const float* __restrict__ wproj,
                        unsigned short* __restrict__ wq_hi, unsigned short* __restrict__ wq_lo,
                        unsigned short* __restrict__ wproj_bf) {
  int i = blockIdx.x * 256 + threadIdx.x;
  if (i < O3_ * C_) {
    unsigned short h, l;
    hilo(wqkv[i], h, l);
    wq_hi[i] = h;
    wq_lo[i] = l;
  }
  if (i < C_ * C_) wproj_bf[i] = f2bf1(wproj[i]);
}

// ---------------- K0b: transpose x [b][c][s] -> xT hi/lo bf16 [b][s][c] ----------------
__global__ void k_xt(const float* __restrict__ x, unsigned short* __restrict__ xT_hi,
                     unsigned short* __restrict__ xT_lo) {
  __shared__ float t[32][33];
  int b = blockIdx.z;
  int c0 = blockIdx.y * 32, s0 = blockIdx.x * 32;
  int tx = threadIdx.x, ty = threadIdx.y;
  const float* xb = x + (size_t)b * C_ * S_;
#pragma unroll
  for (int j = 0; j < 4; ++j)
    t[ty + 8 * j][tx] = xb[(size_t)(c0 + ty + 8 * j) * S_ + s0 + tx];
  __syncthreads();
  unsigned short* hb = xT_hi + (size_t)b * S_ * C_;
  unsigned short* lb = xT_lo + (size_t)b * S_ * C_;
#pragma unroll
  for (int j = 0; j < 4; ++j) {
    unsigned short h, l;
    hilo(t[tx][ty + 8 * j], h, l);
    size_t o = (size_t)(s0 + ty + 8 * j) * C_ + c0 + tx;
    hb[o] = h;
    lb[o] = l;
  }
}

// ---------------- K1: qkv_raw = W_qkv @ x  (split-bf16 3-pass MFMA, ~fp32 accurate) ----------------
__global__ __launch_bounds__(256) void k_qkv(const unsigned short* __restrict__ w_hi,
                                             const unsigned short* __restrict__ w_lo,
                                             const unsigned short* __restrict__ x_hi,
                                             const unsigned short* __restrict__ x_lo,
                                             float* __restrict__ raw) {
  int b = blockIdx.z;
  int m0 = blockIdx.y * 64, n0 = blockIdx.x * 64;
  int tid = threadIdx.x, lane = tid & 63, wid = tid >> 6;
  int l15 = lane & 15, lh = lane >> 4;
  int wm = (wid >> 1) * 32, wn = (wid & 1) * 32;
  const unsigned short* xhb = x_hi + (size_t)b * S_ * C_;
  const unsigned short* xlb = x_lo + (size_t)b * S_ * C_;
  f32x4 acc[2][2] = {};
  int mA = m0 + wm + l15;
  int nB = n0 + wn + l15;
  for (int k0 = 0; k0 < C_; k0 += 32) {
    int kk = k0 + lh * 8;
    short8 a0h = *(const short8*)(w_hi + (size_t)mA * C_ + kk);
    short8 a1h = *(const short8*)(w_hi + (size_t)(mA + 16) * C_ + kk);
    short8 a0l = *(const short8*)(w_lo + (size_t)mA * C_ + kk);
    short8 a1l = *(const short8*)(w_lo + (size_t)(mA + 16) * C_ + kk);
    short8 b0h = *(const short8*)(xhb + (size_t)nB * C_ + kk);
    short8 b1h = *(const short8*)(xhb + (size_t)(nB + 16) * C_ + kk);
    short8 b0l = *(const short8*)(xlb + (size_t)nB * C_ + kk);
    short8 b1l = *(const short8*)(xlb + (size_t)(nB + 16) * C_ + kk);
    acc[0][0] = __builtin_amdgcn_mfma_f32_16x16x32_bf16(a0h, b0h, acc[0][0], 0, 0, 0);
    acc[0][1] = __builtin_amdgcn_mfma_f32_16x16x32_bf16(a0h, b1h, acc[0][1], 0, 0, 0);
    acc[1][0] = __builtin_amdgcn_mfma_f32_16x16x32_bf16(a1h, b0h, acc[1][0], 0, 0, 0);
    acc[1][1] = __builtin_amdgcn_mfma_f32_16x16x32_bf16(a1h, b1h, acc[1][1], 0, 0, 0);
    acc[0][0] = __builtin_amdgcn_mfma_f32_16x16x32_bf16(a0h, b0l, acc[0][0], 0, 0, 0);
    acc[0][1] = __builtin_amdgcn_mfma_f32_16x16x32_bf16(a0h, b1l, acc[0][1], 0, 0, 0);
    acc[1][0] = __builtin_amdgcn_mfma_f32_16x16x32_bf16(a1h, b0l, acc[1][0], 0, 0, 0);
    acc[1][1] = __builtin_amdgcn_mfma_f32_16x16x32_bf16(a1h, b1l, acc[1][1], 0, 0, 0);
    acc[0][0] = __builtin_amdgcn_mfma_f32_16x16x32_bf16(a0l, b0h, acc[0][0], 0, 0, 0);
    acc[0][1] = __builtin_amdgcn_mfma_f32_16x16x32_bf16(a0l, b1h, acc[0][1], 0, 0, 0);
    acc[1][0] = __builtin_amdgcn_mfma_f32_16x16x32_bf16(a1l, b0h, acc[1][0], 0, 0, 0);
    acc[1][1] = __builtin_amdgcn_mfma_f32_16x16x32_bf16(a1l, b1h, acc[1][1], 0, 0, 0);
  }
  float* rawb = raw + (size_t)b * O3_ * S_;
#pragma unroll
  for (int i = 0; i < 2; ++i)
#pragma unroll
    for (int j = 0; j < 2; ++j)
#pragma unroll
      for (int r = 0; r < 4; ++r) {
        int row = m0 + wm + i * 16 + lh * 4 + r;
        int col = n0 + wn + j * 16 + l15;
        rawb[(size_t)row * S_ + col] = acc[i][j][r];
      }
}

// ---------------- K2: depthwise conv + head split + l2norm (+temperature fold) ----------------
DEV float conv3(const float* __restrict__ rp, const float* __restrict__ w, int s) {
  float a = (s > 0) ? rp[s - 1] : 0.f;
  float b = rp[s];
  float c = (s < S_ - 1) ? rp[s + 1] : 0.f;
  return w[0] * a + w[1] * b + w[2] * c;
}

__global__ __launch_bounds__(256) void k_dwnorm(const float* __restrict__ raw,
                                                const float* __restrict__ wdw,
                                                const float* __restrict__ temp,
                                                unsigned short* __restrict__ q_hi,
                                                unsigned short* __restrict__ q_lo,
                                                unsigned short* __restrict__ k_hi,
                                                unsigned short* __restrict__ k_lo,
                                                unsigned short* __restrict__ vt) {
  int b = blockIdx.z, h = blockIdx.y;
  int tid = threadIdx.x;
  int wave = tid >> 6, lane = tid & 63;
  int dg = lane & 7;
  int sl = lane >> 3;
  int s = blockIdx.x * 32 + wave * 8 + sl;
  const float* rawb = raw + (size_t)b * O3_ * S_;
  float tph = temp[h];
  size_t bh = (size_t)(b * H_ + h);
  float qv[4], kv[4], vv[4];
  float sq = 0.f, sk = 0.f;
#pragma unroll
  for (int dd = 0; dd < 4; ++dd) {
    int d = dg * 4 + dd;
    int oq = h * 32 + d;
    float q = conv3(rawb + (size_t)oq * S_, wdw + oq * 3, s);
    qv[dd] = q; sq += q * q;
    int ok = oq + 256;
    float k = conv3(rawb + (size_t)ok * S_, wdw + ok * 3, s);
    kv[dd] = k; sk += k * k;
    int ov = oq + 512;
    vv[dd] = conv3(rawb + (size_t)ov * S_, wdw + ov * 3, s);
  }
#pragma unroll
  for (int m = 1; m < 8; m <<= 1) {
    sq += __shfl_xor(sq, m);
    sk += __shfl_xor(sk, m);
  }
  float iq = tph / fmaxf(sqrtf(sq), 1e-12f);
  float ik = 1.f / fmaxf(sqrtf(sk), 1e-12f);
  size_t base = (bh * S_ + s) * 32 + dg * 4;

  float q0 = qv[0] * iq, q1 = qv[1] * iq, q2 = qv[2] * iq, q3 = qv[3] * iq;
  unsigned qh01 = cvt_pk_bf16(q0, q1), qh23 = cvt_pk_bf16(q2, q3);
  *(uint2v*)(q_hi + base) = uint2v{qh01, qh23};
  float ql0 = q0 - __uint_as_float(qh01 << 16);
  float ql1 = q1 - __uint_as_float(qh01 & 0xFFFF0000u);
  float ql2 = q2 - __uint_as_float(qh23 << 16);
  float ql3 = q3 - __uint_as_float(qh23 & 0xFFFF0000u);
  *(uint2v*)(q_lo + base) = uint2v{cvt_pk_bf16(ql0, ql1), cvt_pk_bf16(ql2, ql3)};

  float k0 = kv[0] * ik, k1 = kv[1] * ik, k2 = kv[2] * ik, k3 = kv[3] * ik;
  unsigned kh01 = cvt_pk_bf16(k0, k1), kh23 = cvt_pk_bf16(k2, k3);
  *(uint2v*)(k_hi + base) = uint2v{kh01, kh23};
  float kl0 = k0 - __uint_as_float(kh01 << 16);
  float kl1 = k1 - __uint_as_float(kh01 & 0xFFFF0000u);
  float kl2 = k2 - __uint_as_float(kh23 << 16);
  float kl3 = k3 - __uint_as_float(kh23 & 0xFFFF0000u);
  *(uint2v*)(k_lo + base) = uint2v{cvt_pk_bf16(kl0, kl1), cvt_pk_bf16(kl2, kl3)};

#pragma unroll
  for (int dd = 0; dd < 4; ++dd) {
    int d = dg * 4 + dd;
    vt[(bh * 32 + d) * S_ + s] = f2bf1(vv[dd]);
  }
}

// ---------------- K3: fused QK^T (split-bf16) -> exact top-512 -> softmax -> PV ----------------
// 1024 thr (16 waves), QT=16; wave w owns row w. 66 KB LDS -> 2 WGs/CU (32 waves/CU).
// Paired column ownership: lane l owns cols 2l,2l+1 of each 128-col slice ->
// extract = ds_read_b64 pairs, P-write = cvt_pk + ds_write_b32 pairs (half the LDS ops of R11).
// v[2k+p] = col (k>>2)*512 + (k&3)*128 + 2*lane + p, k=0..15 (ascending col in (k,lane,p)).
__global__ __launch_bounds__(1024, 8) void k_attn(const unsigned short* __restrict__ q_hi,
                                                  const unsigned short* __restrict__ q_lo,
                                                  const unsigned short* __restrict__ k_hi,
                                                  const unsigned short* __restrict__ k_lo,
                                                  const unsigned short* __restrict__ vt,
                                                  unsigned short* __restrict__ ao) {
  extern __shared__ float smem[];
  __shared__ float is_arr[QT];
  unsigned short* Pb = (unsigned short*)smem;   // P0 at ushort 0, P1 at ushort P1OFF
  float* red = smem;                            // [16][529] partials (alias, after PV done)
  int bid = blockIdx.x;
  int tile = bid & 127;
  int bh = bid >> 7;
  int q0 = tile * QT;
  int tid = threadIdx.x, lane = tid & 63, wv = tid >> 6;  // wv 0..15
  int l15 = lane & 15, lh = lane >> 4;
  const unsigned short* vb = vt + (size_t)bh * 32 * S_;

  size_t qoff = ((size_t)bh * S_ + q0 + l15) * 32 + lh * 8;
  short8 ah = *(const short8*)(q_hi + qoff);
  short8 al = *(const short8*)(q_lo + qoff);
  size_t kbase = (size_t)bh * S_ * 32;

  float v[32];

  // ---- pipelined quarter staging: stage q(n) -> barrier -> {extract q(n) || stage q(n+1)} ----
  short8 kh0, kl0, kh1, kl1;
  {
    const unsigned short* kp = k_hi + kbase + (size_t)(wv * 32 + l15) * 32 + lh * 8;
    const unsigned short* lp = k_lo + kbase + (size_t)(wv * 32 + l15) * 32 + lh * 8;
    kh0 = *(const short8*)(kp);       kl0 = *(const short8*)(lp);
    kh1 = *(const short8*)(kp + 512); kl1 = *(const short8*)(lp + 512);
  }
#pragma unroll
  for (int qq = 0; qq < 4; ++qq) {
    float* buf = smem + (qq & 1) * QBUF;
    {
      f32x4 d0 = {}, d1 = {};
      __builtin_amdgcn_s_setprio(1);
      d0 = __builtin_amdgcn_mfma_f32_16x16x32_bf16(ah, kh0, d0, 0, 0, 0);
      d0 = __builtin_amdgcn_mfma_f32_16x16x32_bf16(ah, kl0, d0, 0, 0, 0);
      d0 = __builtin_amdgcn_mfma_f32_16x16x32_bf16(al, kh0, d0, 0, 0, 0);
      d1 = __builtin_amdgcn_mfma_f32_16x16x32_bf16(ah, kh1, d1, 0, 0, 0);
      d1 = __builtin_amdgcn_mfma_f32_16x16x32_bf16(ah, kl1, d1, 0, 0, 0);
      d1 = __builtin_amdgcn_mfma_f32_16x16x32_bf16(al, kh1, d1, 0, 0, 0);
      __builtin_amdgcn_s_setprio(0);
      int tloc = wv * 32 + l15;
#pragma unroll
      for (int r = 0; r < 4; ++r) {
        buf[(lh * 4 + r) * QSTR + tloc] = d0[r];
        buf[(lh * 4 + r) * QSTR + tloc + 16] = d1[r];
      }
      if (qq < 3) {  // prefetch next quarter's K frags (regs now free)
        int colg = (qq + 1) * QCOLS + wv * 32;
        const unsigned short* kp = k_hi + kbase + (size_t)(colg + l15) * 32 + lh * 8;
        const unsigned short* lp = k_lo + kbase + (size_t)(colg + l15) * 32 + lh * 8;
        kh0 = *(const short8*)(kp);       kl0 = *(const short8*)(lp);
        kh1 = *(const short8*)(kp + 512); kl1 = *(const short8*)(lp + 512);
      }
    }
    __syncthreads();  // buf(qq&1) complete; prior buffer's reads fenced by previous barrier
#pragma unroll
    for (int kk2 = 0; kk2 < 4; ++kk2) {
      f32x2 pr = *(const f32x2*)&buf[wv * QSTR + kk2 * 128 + 2 * lane];
      v[qq * 8 + kk2 * 2] = pr[0];
      v[qq * 8 + kk2 * 2 + 1] = pr[1];
    }
    // next iteration writes the OTHER buffer; write-back to THIS buffer happens at qq+2,
    // after barrier qq+1 which fences these reads.
  }

  // ---- selection (exact top-512) + softmax weights, in registers ----
  {
    float vmax = v[0], vmin = v[0], sum = 0.f, sqs = 0.f;
#pragma unroll
    for (int j = 0; j < 32; ++j) {
      vmax = fmaxf(vmax, v[j]); vmin = fminf(vmin, v[j]);
      sum += v[j]; sqs = fmaf(v[j], v[j], sqs);
    }
#pragma unroll
    for (int m = 1; m < 64; m <<= 1) {
      vmax = fmaxf(vmax, __shfl_xor(vmax, m));
      vmin = fminf(vmin, __shfl_xor(vmin, m));
      sum += __shfl_xor(sum, m);
      sqs += __shfl_xor(sqs, m);
    }
    float mu = sum * (1.f / 2048.f);
    float sig = sqrtf(fmaxf(sqs * (1.f / 2048.f) - mu * mu, 0.f));

    float vlo = vmin - 1e-3f, vhi = vmax;
    float flo = 1536.f, fhi = -512.f;
    int chi = 0;
    float T = vhi;
    bool exact = false;
    int lastside = 0;
    float piv = mu + 0.67449f * sig;
    if (!(piv > vlo && piv < vhi)) piv = 0.5f * (vlo + vhi);
    for (int it = 0; it < 32; ++it) {
      int c = 0;
#pragma unroll
      for (int j = 0; j < 32; ++j)
        c += (int)__popcll(__ballot(v[j] > piv));
      if (c == TOPK) { T = piv; exact = true; break; }
      if (c > TOPK) {
        if (lastside == 1) fhi *= 0.5f;
        vlo = piv; flo = (float)(c - TOPK); lastside = 1;
      } else {
        if (lastside == -1) flo *= 0.5f;
        vhi = piv; fhi = (float)(c - TOPK); chi = c; lastside = -1;
      }
      float npiv;
      if (it == 0 && sig > 1e-20f) {
        float z = (piv - mu) / sig;
        float dens = 0.398942f * __expf(-0.5f * z * z) * (2048.f / sig);
        npiv = piv + (float)(c - TOPK) / fmaxf(dens, 1e-6f);
      } else {
        npiv = vhi - fhi * (vhi - vlo) / (fhi - flo);
      }
      if (!(npiv > vlo && npiv < vhi)) npiv = 0.5f * (vlo + vhi);
      if (!(npiv > vlo && npiv < vhi)) break;
      piv = npiv;
    }
    int cntGT = exact ? TOPK : chi;
    if (!exact) T = vhi;

    unsigned selbits = 0;
#pragma unroll
    for (int j = 0; j < 32; ++j)
      if (v[j] > T) selbits |= (1u << j);
    int need = TOPK - cntGT;
    if (need > 0) {
      // ties by lowest col (jax order). col order: (k, lane, parity) ascending.
      int base = 0;
      unsigned long long lmask = (lane == 0) ? 0ull : (~0ull >> (64 - lane));
#pragma unroll
      for (int k = 0; k < 16; ++k) {
        bool t0 = (v[2 * k] == T), t1 = (v[2 * k + 1] == T);
        unsigned long long m0 = __ballot(t0);
        unsigned long long m1 = __ballot(t1);
        int before = base + (int)__popcll(m0 & lmask) + (int)__popcll(m1 & lmask);
        int r0 = before;
        int r1 = before + (t0 ? 1 : 0);
        if (t0 && r0 < need) selbits |= (1u << (2 * k));
        if (t1 && r1 < need) selbits |= (1u << (2 * k + 1));
        base += (int)__popcll(m0) + (int)__popcll(m1);
      }
    }

    float ssum = 0.f;
#pragma unroll
    for (int j = 0; j < 32; ++j) {
      float e = ((selbits >> j) & 1u) ? __expf(v[j] - vmax) : 0.f;
      v[j] = e;
      ssum += e;
    }
#pragma unroll
    for (int m = 1; m < 64; m <<= 1) ssum += __shfl_xor(ssum, m);
    if (lane == 0) is_arr[wv] = 1.f / ssum;
  }

  // ---- P0 write; bar; {PV0 || P1 write}; bar; PV1 ----
  // Swizzle: idx = (base + row*1024 + col) ^ (8*(row&7)); bases 64-ushort aligned -> bijective.
  // Half h holds k in [8h, 8h+8); local col = ((k-8h)>>2)*512 + (k&3)*128 + 2*lane + p.
  // Paired dword writes: lc even, swz multiple of 8 -> (idx^swz) even, dword-aligned.
  f32x4 acc0 = {}, acc1 = {};
  int swz_w = (wv & 7) << 3;
  int swz_r = (l15 & 7) << 3;
#pragma unroll
  for (int kk = 0; kk < 8; ++kk) {   // P0: v[0..15]
    int lc = (kk >> 2) * 512 + (kk & 3) * 128 + 2 * lane;
    unsigned pk = cvt_pk_bf16(v[2 * kk], v[2 * kk + 1]);
    *(unsigned*)&Pb[(wv * PSTH + lc) ^ swz_w] = pk;
  }
  __syncthreads();  // P0 ready
  {
    // P1 write (independent of PV0; fills barrier-to-barrier span)
#pragma unroll
    for (int kk = 0; kk < 8; ++kk) {
      int lc = (kk >> 2) * 512 + (kk & 3) * 128 + 2 * lane;
      unsigned pk = cvt_pk_bf16(v[16 + 2 * kk], v[16 + 2 * kk + 1]);
      *(unsigned*)&Pb[P1OFF + ((wv * PSTH + lc) ^ swz_w)] = pk;
    }
    // PV0
    const unsigned short* v0p = vb + (size_t)l15 * S_ + wv * 64 + lh * 8;
    const unsigned short* v1p = v0p + 16 * S_;
#pragma unroll
    for (int kt = 0; kt < 2; ++kt) {
      int lc = wv * 64 + kt * 32 + lh * 8;
      short8 a = *(const short8*)(Pb + ((l15 * PSTH + lc) ^ swz_r));
      short8 b0 = *(const short8*)(v0p + kt * 32);
      short8 b1 = *(const short8*)(v1p + kt * 32);
      __builtin_amdgcn_s_setprio(1);
      acc0 = __builtin_amdgcn_mfma_f32_16x16x32_bf16(a, b0, acc0, 0, 0, 0);
      acc1 = __builtin_amdgcn_mfma_f32_16x16x32_bf16(a, b1, acc1, 0, 0, 0);
      __builtin_amdgcn_s_setprio(0);
    }
  }
  __syncthreads();  // P1 ready (and PV0 reads of P0 done)
  {
    const unsigned short* v0p = vb + (size_t)l15 * S_ + 1024 + wv * 64 + lh * 8;
    const unsigned short* v1p = v0p + 16 * S_;
#pragma unroll
    for (int kt = 0; kt < 2; ++kt) {
      int lc = wv * 64 + kt * 32 + lh * 8;
      short8 a = *(const short8*)(Pb + P1OFF + ((l15 * PSTH + lc) ^ swz_r));
      short8 b0 = *(const short8*)(v0p + kt * 32);
      short8 b1 = *(const short8*)(v1p + kt * 32);
      __builtin_amdgcn_s_setprio(1);
      acc0 = __builtin_amdgcn_mfma_f32_16x16x32_bf16(a, b0, acc0, 0, 0, 0);
      acc1 = __builtin_amdgcn_mfma_f32_16x16x32_bf16(a, b1, acc1, 0, 0, 0);
      __builtin_amdgcn_s_setprio(0);
    }
  }
  __syncthreads();  // PV1 reads done; red region (aliases P) safe

  // ---- cross-wave reduction of 16 partial out(16x32) tiles ----
#pragma unroll
  for (int r = 0; r < 4; ++r) {
    red[wv * 529 + (lh * 4 + r) * 33 + l15] = acc0[r];
    red[wv * 529 + (lh * 4 + r) * 33 + 16 + l15] = acc1[r];
  }
  __syncthreads();
  if (tid < 512) {
    int row = tid >> 5, d = tid & 31;
    float s = 0.f;
#pragma unroll
    for (int w = 0; w < 16; ++w) s += red[w * 529 + row * 33 + d];
    s *= is_arr[row];
    ao[((size_t)bh * S_ + q0 + row) * 32 + d] = f2bf1(s);
  }
}

// ---------------- K4: output projection ----------------
__global__ __launch_bounds__(256) void k_proj(const unsigned short* __restrict__ wbf,
                                              const unsigned short* __restrict__ ao,
                                              float* __restrict__ out) {
  int b = blockIdx.z;
  int m0 = blockIdx.y * 64, n0 = blockIdx.x * 64;
  int tid = threadIdx.x, lane = tid & 63, wid = tid >> 6;
  int l15 = lane & 15, lh = lane >> 4;
  int wm = (wid >> 1) * 32, wn = (wid & 1) * 32;
  const unsigned short* aob = ao + (size_t)b * H_ * S_ * 32;
  f32x4 acc[2][2] = {};
  int mA = m0 + wm + l15;
  int nB = n0 + wn + l15;
  for (int k0 = 0; k0 < C_; k0 += 32) {
    int kk = k0 + lh * 8;
    int hh = kk >> 5;
    int dd = kk & 31;
    short8 a0 = *(const short8*)(wbf + (size_t)mA * C_ + kk);
    short8 a1 = *(const short8*)(wbf + (size_t)(mA + 16) * C_ + kk);
    short8 b0 = *(const short8*)(aob + ((size_t)hh * S_ + nB) * 32 + dd);
    short8 b1 = *(const short8*)(aob + ((size_t)hh * S_ + nB + 16) * 32 + dd);
    acc[0][0] = __builtin_amdgcn_mfma_f32_16x16x32_bf16(a0, b0, acc[0][0], 0, 0, 0);
    acc[0][1] = __builtin_amdgcn_mfma_f32_16x16x32_bf16(a0, b1, acc[0][1], 0, 0, 0);
    acc[1][0] = __builtin_amdgcn_mfma_f32_16x16x32_bf16(a1, b0, acc[1][0], 0, 0, 0);
    acc[1][1] = __builtin_amdgcn_mfma_f32_16x16x32_bf16(a1, b1, acc[1][1], 0, 0, 0);
  }
  float* ob = out + (size_t)b * C_ * S_;
#pragma unroll
  for (int i = 0; i < 2; ++i)
#pragma unroll
    for (int j = 0; j < 2; ++j)
#pragma unroll
      for (int r = 0; r < 4; ++r) {
        int row = m0 + wm + i * 16 + lh * 4 + r;
        int col = n0 + wn + j * 16 + l15;
        ob[(size_t)row * S_ + col] = acc[i][j][r];
      }
}

extern "C" void kernel_launch(void* const* d_in, const int* in_sizes, int n_in,
                              void* d_out, int out_size, void* d_ws, size_t ws_size,
                              hipStream_t stream) {
  const float* x = (const float*)d_in[0];
  const float* wqkv = (const float*)d_in[1];
  const float* wdw = (const float*)d_in[2];
  const float* wproj = (const float*)d_in[3];
  const float* temp = (const float*)d_in[4];
  float* out = (float*)d_out;

  char* ws = (char*)d_ws;
  size_t off = 0;
  auto alloc = [&](size_t bytes) -> void* {
    void* p = ws + off;
    off += (bytes + 255) & ~(size_t)255;
    return p;
  };
  unsigned short* x_hi     = (unsigned short*)alloc((size_t)B_ * S_ * C_ * 2);
  unsigned short* x_lo     = (unsigned short*)alloc((size_t)B_ * S_ * C_ * 2);
  unsigned short* wq_hi    = (unsigned short*)alloc((size_t)O3_ * C_ * 2);
  unsigned short* wq_lo    = (unsigned short*)alloc((size_t)O3_ * C_ * 2);
  unsigned short* wproj_bf = (unsigned short*)alloc((size_t)C_ * C_ * 2);
  float*          raw      = (float*)alloc((size_t)B_ * O3_ * S_ * 4);
  unsigned short* k_hi     = (unsigned short*)alloc((size_t)B_ * H_ * S_ * 32 * 2);
  unsigned short* k_lo     = (unsigned short*)alloc((size_t)B_ * H_ * S_ * 32 * 2);
  unsigned short* vt       = (unsigned short*)alloc((size_t)B_ * H_ * 32 * S_ * 2);
  unsigned short* q_hi     = x_hi;                 // alias (x dead after k_qkv)
  unsigned short* q_lo     = x_lo;                 // alias
  unsigned short* ao       = (unsigned short*)raw; // alias (raw dead after k_dwnorm)

  (void)hipFuncSetAttribute(reinterpret_cast<const void*>(k_attn),
                            hipFuncAttributeMaxDynamicSharedMemorySize, (int)K3_LDS_BYTES);

  k_convw<<<dim3((O3_ * C_ + 255) / 256), dim3(256), 0, stream>>>(wqkv, wproj, wq_hi, wq_lo, wproj_bf);
  k_xt<<<dim3(S_ / 32, C_ / 32, B_), dim3(32, 8), 0, stream>>>(x, x_hi, x_lo);
  k_qkv<<<dim3(S_ / 64, O3_ / 64, B_), dim3(256), 0, stream>>>(wq_hi, wq_lo, x_hi, x_lo, raw);
  k_dwnorm<<<dim3(S_ / 32, H_, B_), dim3(256), 0, stream>>>(raw, wdw, temp, q_hi, q_lo, k_hi, k_lo, vt);
  k_attn<<<dim3(B_ * H_ * (S_ / QT)), dim3(1024), K3_LDS_BYTES, stream>>>(q_hi, q_lo, k_hi, k_lo, vt, ao);
  k_proj<<<dim3(S_ / 64, C_ / 64, B_), dim3(256), 0, stream>>>(wproj_bf, ao, out);
}

// Round 13
// 252.016 us; speedup vs baseline: 1.2157x; 1.0838x over previous
//
#include <hip/hip_runtime.h>
#include <math.h>

typedef __attribute__((ext_vector_type(8))) short short8;
typedef __attribute__((ext_vector_type(4))) float f32x4;
typedef __attribute__((ext_vector_type(2))) float f32x2;
typedef __attribute__((ext_vector_type(2))) unsigned int uint2v;
typedef __attribute__((ext_vector_type(4))) unsigned int uint4v;

#define DEV __device__ __forceinline__

static constexpr int B_ = 4, C_ = 256, S_ = 2048, H_ = 8, O3_ = 768;
static constexpr int TOPK = 512;
static constexpr int QT = 16;           // q rows per workgroup in attention
static constexpr int QCOLS = 512;       // score cols per quarter pass
static constexpr int QSTR = 516;        // fp32 score row stride (quarter buffer)
static constexpr int QBUF = 16 * QSTR;  // floats per quarter buffer (8256)
static constexpr int PSTH = 1024;       // bf16 P half row stride
static constexpr int P1OFF = 2 * QBUF;  // ushort offset of P1 = 16512 (64-aligned -> swizzle bijective)
static constexpr size_t K3_LDS_BYTES = (size_t)2 * QBUF * 4;  // 66048 B -> 2 WGs/CU
static constexpr int XSTR = 40;         // k_qkv LDS row stride (ushorts); 80B, 16B-aligned

DEV unsigned cvt_pk_bf16(float a, float b) {
  unsigned r;
  asm("v_cvt_pk_bf16_f32 %0, %1, %2" : "=v"(r) : "v"(a), "v"(b));
  return r;  // lo16 = bf16(a), hi16 = bf16(b)
}
DEV unsigned short f2bf1(float f) { return (unsigned short)(cvt_pk_bf16(f, f) & 0xFFFFu); }
DEV float bf2f(unsigned short h) { return __uint_as_float(((unsigned)h) << 16); }
DEV void hilo(float f, unsigned short& h, unsigned short& l) {
  unsigned p = cvt_pk_bf16(f, f);
  h = (unsigned short)p;
  float r = f - __uint_as_float(p << 16);
  l = (unsigned short)(cvt_pk_bf16(r, r) & 0xFFFFu);
}

// ---------------- K0a: weights -> bf16 hi/lo (qkv), bf16 (proj) ----------------
__global__ void k_convw(const float* __restrict__ wqkv, const float* __restrict__ wproj,
                        unsigned short* __restrict__ wq_hi, unsigned short* __restrict__ wq_lo,
                        unsigned short* __restrict__ wproj_bf) {
  int i = blockIdx.x * 256 + threadIdx.x;
  if (i < O3_ * C_) {
    unsigned short h, l;
    hilo(wqkv[i], h, l);
    wq_hi[i] = h;
    wq_lo[i] = l;
  }
  if (i < C_ * C_) wproj_bf[i] = f2bf1(wproj[i]);
}

// ---------------- K1: qkv_raw = W_qkv @ x, transpose fused (split-bf16 3-pass MFMA) ----------------
// x read directly as [c][s] fp32; hilo-converted and staged transposed [s][c] bf16 in LDS.
// Each thread stages 8 consecutive c's of one s: 8 coalesced global loads + 2 ds_write_b128.
__global__ __launch_bounds__(256) void k_qkv(const unsigned short* __restrict__ w_hi,
                                             const unsigned short* __restrict__ w_lo,
                                             const float* __restrict__ x,
                                             float* __restrict__ raw) {
  __shared__ unsigned short xh[2][64 * XSTR];
  __shared__ unsigned short xl[2][64 * XSTR];
  int b = blockIdx.z;
  int m0 = blockIdx.y * 64, n0 = blockIdx.x * 64;
  int tid = threadIdx.x, lane = tid & 63, wid = tid >> 6;
  int l15 = lane & 15, lh = lane >> 4;
  int wm = (wid >> 1) * 32, wn = (wid & 1) * 32;
  int sl = tid & 63, cg = tid >> 6;   // staging role: s-local, c-group (8 c's)
  const float* xb = x + (size_t)b * C_ * S_ + n0 + sl;

  f32x4 acc[2][2] = {};
  int mA = m0 + wm + l15;

  // stage K-step tile into buffer bufi: c in [k0, k0+32), s in [n0, n0+64)
  auto stage = [&](int k0, int bufi) {
    float f[8];
#pragma unroll
    for (int j = 0; j < 8; ++j)
      f[j] = xb[(size_t)(k0 + cg * 8 + j) * S_];
    unsigned h[4], l[4];
#pragma unroll
    for (int j = 0; j < 4; ++j) {
      h[j] = cvt_pk_bf16(f[2 * j], f[2 * j + 1]);
      float r0 = f[2 * j] - __uint_as_float(h[j] << 16);
      float r1 = f[2 * j + 1] - __uint_as_float(h[j] & 0xFFFF0000u);
      l[j] = cvt_pk_bf16(r0, r1);
    }
    int o = sl * XSTR + cg * 8;
    *(uint4v*)&xh[bufi][o] = uint4v{h[0], h[1], h[2], h[3]};
    *(uint4v*)&xl[bufi][o] = uint4v{l[0], l[1], l[2], l[3]};
  };

  stage(0, 0);
  for (int ks = 0; ks < 8; ++ks) {
    __syncthreads();  // buffer (ks&1) staged; reads of buffer ((ks+1)&1) from step ks-1 done
    if (ks < 7) stage((ks + 1) * 32, (ks ^ 1) & 1);
    int kk = lh * 8;
    int k0 = ks * 32;
    const unsigned short* bh0 = &xh[ks & 1][(wn + l15) * XSTR + kk];
    const unsigned short* bh1 = &xh[ks & 1][(wn + 16 + l15) * XSTR + kk];
    const unsigned short* bl0 = &xl[ks & 1][(wn + l15) * XSTR + kk];
    const unsigned short* bl1 = &xl[ks & 1][(wn + 16 + l15) * XSTR + kk];
    short8 b0h = *(const short8*)bh0;
    short8 b1h = *(const short8*)bh1;
    short8 b0l = *(const short8*)bl0;
    short8 b1l = *(const short8*)bl1;
    short8 a0h = *(const short8*)(w_hi + (size_t)mA * C_ + k0 + kk);
    short8 a1h = *(const short8*)(w_hi + (size_t)(mA + 16) * C_ + k0 + kk);
    short8 a0l = *(const short8*)(w_lo + (size_t)mA * C_ + k0 + kk);
    short8 a1l = *(const short8*)(w_lo + (size_t)(mA + 16) * C_ + k0 + kk);
    acc[0][0] = __builtin_amdgcn_mfma_f32_16x16x32_bf16(a0h, b0h, acc[0][0], 0, 0, 0);
    acc[0][1] = __builtin_amdgcn_mfma_f32_16x16x32_bf16(a0h, b1h, acc[0][1], 0, 0, 0);
    acc[1][0] = __builtin_amdgcn_mfma_f32_16x16x32_bf16(a1h, b0h, acc[1][0], 0, 0, 0);
    acc[1][1] = __builtin_amdgcn_mfma_f32_16x16x32_bf16(a1h, b1h, acc[1][1], 0, 0, 0);
    acc[0][0] = __builtin_amdgcn_mfma_f32_16x16x32_bf16(a0h, b0l, acc[0][0], 0, 0, 0);
    acc[0][1] = __builtin_amdgcn_mfma_f32_16x16x32_bf16(a0h, b1l, acc[0][1], 0, 0, 0);
    acc[1][0] = __builtin_amdgcn_mfma_f32_16x16x32_bf16(a1h, b0l, acc[1][0], 0, 0, 0);
    acc[1][1] = __builtin_amdgcn_mfma_f32_16x16x32_bf16(a1h, b1l, acc[1][1], 0, 0, 0);
    acc[0][0] = __builtin_amdgcn_mfma_f32_16x16x32_bf16(a0l, b0h, acc[0][0], 0, 0, 0);
    acc[0][1] = __builtin_amdgcn_mfma_f32_16x16x32_bf16(a0l, b1h, acc[0][1], 0, 0, 0);
    acc[1][0] = __builtin_amdgcn_mfma_f32_16x16x32_bf16(a1l, b0h, acc[1][0], 0, 0, 0);
    acc[1][1] = __builtin_amdgcn_mfma_f32_16x16x32_bf16(a1l, b1h, acc[1][1], 0, 0, 0);
  }
  float* rawb = raw + (size_t)b * O3_ * S_;
#pragma unroll
  for (int i = 0; i < 2; ++i)
#pragma unroll
    for (int j = 0; j < 2; ++j)
#pragma unroll
      for (int r = 0; r < 4; ++r) {
        int row = m0 + wm + i * 16 + lh * 4 + r;
        int col = n0 + wn + j * 16 + l15;
        rawb[(size_t)row * S_ + col] = acc[i][j][r];
      }
}

// ---------------- K2: depthwise conv + head split + l2norm (+temperature fold) ----------------
DEV float conv3(const float* __restrict__ rp, const float* __restrict__ w, int s) {
  float a = (s > 0) ? rp[s - 1] : 0.f;
  float b = rp[s];
  float c = (s < S_ - 1) ? rp[s + 1] : 0.f;
  return w[0] * a + w[1] * b + w[2] * c;
}

__global__ __launch_bounds__(256) void k_dwnorm(const float* __restrict__ raw,
                                                const float* __restrict__ wdw,
                                                const float* __restrict__ temp,
                                                unsigned short* __restrict__ q_hi,
                                                unsigned short* __restrict__ q_lo,
                                                unsigned short* __restrict__ k_hi,
                                                unsigned short* __restrict__ k_lo,
                                                unsigned short* __restrict__ vt) {
  int b = blockIdx.z, h = blockIdx.y;
  int tid = threadIdx.x;
  int wave = tid >> 6, lane = tid & 63;
  int dg = lane & 7;
  int sl = lane >> 3;
  int s = blockIdx.x * 32 + wave * 8 + sl;
  const float* rawb = raw + (size_t)b * O3_ * S_;
  float tph = temp[h];
  size_t bh = (size_t)(b * H_ + h);
  float qv[4], kv[4], vv[4];
  float sq = 0.f, sk = 0.f;
#pragma unroll
  for (int dd = 0; dd < 4; ++dd) {
    int d = dg * 4 + dd;
    int oq = h * 32 + d;
    float q = conv3(rawb + (size_t)oq * S_, wdw + oq * 3, s);
    qv[dd] = q; sq += q * q;
    int ok = oq + 256;
    float k = conv3(rawb + (size_t)ok * S_, wdw + ok * 3, s);
    kv[dd] = k; sk += k * k;
    int ov = oq + 512;
    vv[dd] = conv3(rawb + (size_t)ov * S_, wdw + ov * 3, s);
  }
#pragma unroll
  for (int m = 1; m < 8; m <<= 1) {
    sq += __shfl_xor(sq, m);
    sk += __shfl_xor(sk, m);
  }
  float iq = tph / fmaxf(sqrtf(sq), 1e-12f);
  float ik = 1.f / fmaxf(sqrtf(sk), 1e-12f);
  size_t base = (bh * S_ + s) * 32 + dg * 4;

  float q0 = qv[0] * iq, q1 = qv[1] * iq, q2 = qv[2] * iq, q3 = qv[3] * iq;
  unsigned qh01 = cvt_pk_bf16(q0, q1), qh23 = cvt_pk_bf16(q2, q3);
  *(uint2v*)(q_hi + base) = uint2v{qh01, qh23};
  float ql0 = q0 - __uint_as_float(qh01 << 16);
  float ql1 = q1 - __uint_as_float(qh01 & 0xFFFF0000u);
  float ql2 = q2 - __uint_as_float(qh23 << 16);
  float ql3 = q3 - __uint_as_float(qh23 & 0xFFFF0000u);
  *(uint2v*)(q_lo + base) = uint2v{cvt_pk_bf16(ql0, ql1), cvt_pk_bf16(ql2, ql3)};

  float k0 = kv[0] * ik, k1 = kv[1] * ik, k2 = kv[2] * ik, k3 = kv[3] * ik;
  unsigned kh01 = cvt_pk_bf16(k0, k1), kh23 = cvt_pk_bf16(k2, k3);
  *(uint2v*)(k_hi + base) = uint2v{kh01, kh23};
  float kl0 = k0 - __uint_as_float(kh01 << 16);
  float kl1 = k1 - __uint_as_float(kh01 & 0xFFFF0000u);
  float kl2 = k2 - __uint_as_float(kh23 << 16);
  float kl3 = k3 - __uint_as_float(kh23 & 0xFFFF0000u);
  *(uint2v*)(k_lo + base) = uint2v{cvt_pk_bf16(kl0, kl1), cvt_pk_bf16(kl2, kl3)};

#pragma unroll
  for (int dd = 0; dd < 4; ++dd) {
    int d = dg * 4 + dd;
    vt[(bh * 32 + d) * S_ + s] = f2bf1(vv[dd]);
  }
}

// ---------------- K3: fused QK^T (split-bf16) -> exact top-512 -> softmax -> PV ----------------
// (identical to R12: 1024 thr, pipelined quarter staging, paired-column selection, dbuf P)
__global__ __launch_bounds__(1024, 8) void k_attn(const unsigned short* __restrict__ q_hi,
                                                  const unsigned short* __restrict__ q_lo,
                                                  const unsigned short* __restrict__ k_hi,
                                                  const unsigned short* __restrict__ k_lo,
                                                  const unsigned short* __restrict__ vt,
                                                  unsigned short* __restrict__ ao) {
  extern __shared__ float smem[];
  __shared__ float is_arr[QT];
  unsigned short* Pb = (unsigned short*)smem;
  float* red = smem;
  int bid = blockIdx.x;
  int tile = bid & 127;
  int bh = bid >> 7;
  int q0 = tile * QT;
  int tid = threadIdx.x, lane = tid & 63, wv = tid >> 6;
  int l15 = lane & 15, lh = lane >> 4;
  const unsigned short* vb = vt + (size_t)bh * 32 * S_;

  size_t qoff = ((size_t)bh * S_ + q0 + l15) * 32 + lh * 8;
  short8 ah = *(const short8*)(q_hi + qoff);
  short8 al = *(const short8*)(q_lo + qoff);
  size_t kbase = (size_t)bh * S_ * 32;

  float v[32];

  short8 kh0, kl0, kh1, kl1;
  {
    const unsigned short* kp = k_hi + kbase + (size_t)(wv * 32 + l15) * 32 + lh * 8;
    const unsigned short* lp = k_lo + kbase + (size_t)(wv * 32 + l15) * 32 + lh * 8;
    kh0 = *(const short8*)(kp);       kl0 = *(const short8*)(lp);
    kh1 = *(const short8*)(kp + 512); kl1 = *(const short8*)(lp + 512);
  }
#pragma unroll
  for (int qq = 0; qq < 4; ++qq) {
    float* buf = smem + (qq & 1) * QBUF;
    {
      f32x4 d0 = {}, d1 = {};
      __builtin_amdgcn_s_setprio(1);
      d0 = __builtin_amdgcn_mfma_f32_16x16x32_bf16(ah, kh0, d0, 0, 0, 0);
      d0 = __builtin_amdgcn_mfma_f32_16x16x32_bf16(ah, kl0, d0, 0, 0, 0);
      d0 = __builtin_amdgcn_mfma_f32_16x16x32_bf16(al, kh0, d0, 0, 0, 0);
      d1 = __builtin_amdgcn_mfma_f32_16x16x32_bf16(ah, kh1, d1, 0, 0, 0);
      d1 = __builtin_amdgcn_mfma_f32_16x16x32_bf16(ah, kl1, d1, 0, 0, 0);
      d1 = __builtin_amdgcn_mfma_f32_16x16x32_bf16(al, kh1, d1, 0, 0, 0);
      __builtin_amdgcn_s_setprio(0);
      int tloc = wv * 32 + l15;
#pragma unroll
      for (int r = 0; r < 4; ++r) {
        buf[(lh * 4 + r) * QSTR + tloc] = d0[r];
        buf[(lh * 4 + r) * QSTR + tloc + 16] = d1[r];
      }
      if (qq < 3) {
        int colg = (qq + 1) * QCOLS + wv * 32;
        const unsigned short* kp = k_hi + kbase + (size_t)(colg + l15) * 32 + lh * 8;
        const unsigned short* lp = k_lo + kbase + (size_t)(colg + l15) * 32 + lh * 8;
        kh0 = *(const short8*)(kp);       kl0 = *(const short8*)(lp);
        kh1 = *(const short8*)(kp + 512); kl1 = *(const short8*)(lp + 512);
      }
    }
    __syncthreads();
#pragma unroll
    for (int kk2 = 0; kk2 < 4; ++kk2) {
      f32x2 pr = *(const f32x2*)&buf[wv * QSTR + kk2 * 128 + 2 * lane];
      v[qq * 8 + kk2 * 2] = pr[0];
      v[qq * 8 + kk2 * 2 + 1] = pr[1];
    }
  }

  {
    float vmax = v[0], vmin = v[0], sum = 0.f, sqs = 0.f;
#pragma unroll
    for (int j = 0; j < 32; ++j) {
      vmax = fmaxf(vmax, v[j]); vmin = fminf(vmin, v[j]);
      sum += v[j]; sqs = fmaf(v[j], v[j], sqs);
    }
#pragma unroll
    for (int m = 1; m < 64; m <<= 1) {
      vmax = fmaxf(vmax, __shfl_xor(vmax, m));
      vmin = fminf(vmin, __shfl_xor(vmin, m));
      sum += __shfl_xor(sum, m);
      sqs += __shfl_xor(sqs, m);
    }
    float mu = sum * (1.f / 2048.f);
    float sig = sqrtf(fmaxf(sqs * (1.f / 2048.f) - mu * mu, 0.f));

    float vlo = vmin - 1e-3f, vhi = vmax;
    float flo = 1536.f, fhi = -512.f;
    int chi = 0;
    float T = vhi;
    bool exact = false;
    int lastside = 0;
    float piv = mu + 0.67449f * sig;
    if (!(piv > vlo && piv < vhi)) piv = 0.5f * (vlo + vhi);
    for (int it = 0; it < 32; ++it) {
      int c = 0;
#pragma unroll
      for (int j = 0; j < 32; ++j)
        c += (int)__popcll(__ballot(v[j] > piv));
      if (c == TOPK) { T = piv; exact = true; break; }
      if (c > TOPK) {
        if (lastside == 1) fhi *= 0.5f;
        vlo = piv; flo = (float)(c - TOPK); lastside = 1;
      } else {
        if (lastside == -1) flo *= 0.5f;
        vhi = piv; fhi = (float)(c - TOPK); chi = c; lastside = -1;
      }
      float npiv;
      if (it == 0 && sig > 1e-20f) {
        float z = (piv - mu) / sig;
        float dens = 0.398942f * __expf(-0.5f * z * z) * (2048.f / sig);
        npiv = piv + (float)(c - TOPK) / fmaxf(dens, 1e-6f);
      } else {
        npiv = vhi - fhi * (vhi - vlo) / (fhi - flo);
      }
      if (!(npiv > vlo && npiv < vhi)) npiv = 0.5f * (vlo + vhi);
      if (!(npiv > vlo && npiv < vhi)) break;
      piv = npiv;
    }
    int cntGT = exact ? TOPK : chi;
    if (!exact) T = vhi;

    unsigned selbits = 0;
#pragma unroll
    for (int j = 0; j < 32; ++j)
      if (v[j] > T) selbits |= (1u << j);
    int need = TOPK - cntGT;
    if (need > 0) {
      int base = 0;
      unsigned long long lmask = (lane == 0) ? 0ull : (~0ull >> (64 - lane));
#pragma unroll
      for (int k = 0; k < 16; ++k) {
        bool t0 = (v[2 * k] == T), t1 = (v[2 * k + 1] == T);
        unsigned long long m0 = __ballot(t0);
        unsigned long long m1 = __ballot(t1);
        int before = base + (int)__popcll(m0 & lmask) + (int)__popcll(m1 & lmask);
        int r0 = before;
        int r1 = before + (t0 ? 1 : 0);
        if (t0 && r0 < need) selbits |= (1u << (2 * k));
        if (t1 && r1 < need) selbits |= (1u << (2 * k + 1));
        base += (int)__popcll(m0) + (int)__popcll(m1);
      }
    }

    float ssum = 0.f;
#pragma unroll
    for (int j = 0; j < 32; ++j) {
      float e = ((selbits >> j) & 1u) ? __expf(v[j] - vmax) : 0.f;
      v[j] = e;
      ssum += e;
    }
#pragma unroll
    for (int m = 1; m < 64; m <<= 1) ssum += __shfl_xor(ssum, m);
    if (lane == 0) is_arr[wv] = 1.f / ssum;
  }

  f32x4 acc0 = {}, acc1 = {};
  int swz_w = (wv & 7) << 3;
  int swz_r = (l15 & 7) << 3;
#pragma unroll
  for (int kk = 0; kk < 8; ++kk) {
    int lc = (kk >> 2) * 512 + (kk & 3) * 128 + 2 * lane;
    unsigned pk = cvt_pk_bf16(v[2 * kk], v[2 * kk + 1]);
    *(unsigned*)&Pb[(wv * PSTH + lc) ^ swz_w] = pk;
  }
  __syncthreads();
  {
#pragma unroll
    for (int kk = 0; kk < 8; ++kk) {
      int lc = (kk >> 2) * 512 + (kk & 3) * 128 + 2 * lane;
      unsigned pk = cvt_pk_bf16(v[16 + 2 * kk], v[16 + 2 * kk + 1]);
      *(unsigned*)&Pb[P1OFF + ((wv * PSTH + lc) ^ swz_w)] = pk;
    }
    const unsigned short* v0p = vb + (size_t)l15 * S_ + wv * 64 + lh * 8;
    const unsigned short* v1p = v0p + 16 * S_;
#pragma unroll
    for (int kt = 0; kt < 2; ++kt) {
      int lc = wv * 64 + kt * 32 + lh * 8;
      short8 a = *(const short8*)(Pb + ((l15 * PSTH + lc) ^ swz_r));
      short8 b0 = *(const short8*)(v0p + kt * 32);
      short8 b1 = *(const short8*)(v1p + kt * 32);
      __builtin_amdgcn_s_setprio(1);
      acc0 = __builtin_amdgcn_mfma_f32_16x16x32_bf16(a, b0, acc0, 0, 0, 0);
      acc1 = __builtin_amdgcn_mfma_f32_16x16x32_bf16(a, b1, acc1, 0, 0, 0);
      __builtin_amdgcn_s_setprio(0);
    }
  }
  __syncthreads();
  {
    const unsigned short* v0p = vb + (size_t)l15 * S_ + 1024 + wv * 64 + lh * 8;
    const unsigned short* v1p = v0p + 16 * S_;
#pragma unroll
    for (int kt = 0; kt < 2; ++kt) {
      int lc = wv * 64 + kt * 32 + lh * 8;
      short8 a = *(const short8*)(Pb + P1OFF + ((l15 * PSTH + lc) ^ swz_r));
      short8 b0 = *(const short8*)(v0p + kt * 32);
      short8 b1 = *(const short8*)(v1p + kt * 32);
      __builtin_amdgcn_s_setprio(1);
      acc0 = __builtin_amdgcn_mfma_f32_16x16x32_bf16(a, b0, acc0, 0, 0, 0);
      acc1 = __builtin_amdgcn_mfma_f32_16x16x32_bf16(a, b1, acc1, 0, 0, 0);
      __builtin_amdgcn_s_setprio(0);
    }
  }
  __syncthreads();

#pragma unroll
  for (int r = 0; r < 4; ++r) {
    red[wv * 529 + (lh * 4 + r) * 33 + l15] = acc0[r];
    red[wv * 529 + (lh * 4 + r) * 33 + 16 + l15] = acc1[r];
  }
  __syncthreads();
  if (tid < 512) {
    int row = tid >> 5, d = tid & 31;
    float s = 0.f;
#pragma unroll
    for (int w = 0; w < 16; ++w) s += red[w * 529 + row * 33 + d];
    s *= is_arr[row];
    ao[((size_t)bh * S_ + q0 + row) * 32 + d] = f2bf1(s);
  }
}

// ---------------- K4: output projection ----------------
__global__ __launch_bounds__(256) void k_proj(const unsigned short* __restrict__ wbf,
                                              const unsigned short* __restrict__ ao,
                                              float* __restrict__ out) {
  int b = blockIdx.z;
  int m0 = blockIdx.y * 64, n0 = blockIdx.x * 64;
  int tid = threadIdx.x, lane = tid & 63, wid = tid >> 6;
  int l15 = lane & 15, lh = lane >> 4;
  int wm = (wid >> 1) * 32, wn = (wid & 1) * 32;
  const unsigned short* aob = ao + (size_t)b * H_ * S_ * 32;
  f32x4 acc[2][2] = {};
  int mA = m0 + wm + l15;
  int nB = n0 + wn + l15;
  for (int k0 = 0; k0 < C_; k0 += 32) {
    int kk = k0 + lh * 8;
    int hh = kk >> 5;
    int dd = kk & 31;
    short8 a0 = *(const short8*)(wbf + (size_t)mA * C_ + kk);
    short8 a1 = *(const short8*)(wbf + (size_t)(mA + 16) * C_ + kk);
    short8 b0 = *(const short8*)(aob + ((size_t)hh * S_ + nB) * 32 + dd);
    short8 b1 = *(const short8*)(aob + ((size_t)hh * S_ + nB + 16) * 32 + dd);
    acc[0][0] = __builtin_amdgcn_mfma_f32_16x16x32_bf16(a0, b0, acc[0][0], 0, 0, 0);
    acc[0][1] = __builtin_amdgcn_mfma_f32_16x16x32_bf16(a0, b1, acc[0][1], 0, 0, 0);
    acc[1][0] = __builtin_amdgcn_mfma_f32_16x16x32_bf16(a1, b0, acc[1][0], 0, 0, 0);
    acc[1][1] = __builtin_amdgcn_mfma_f32_16x16x32_bf16(a1, b1, acc[1][1], 0, 0, 0);
  }
  float* ob = out + (size_t)b * C_ * S_;
#pragma unroll
  for (int i = 0; i < 2; ++i)
#pragma unroll
    for (int j = 0; j < 2; ++j)
#pragma unroll
      for (int r = 0; r < 4; ++r) {
        int row = m0 + wm + i * 16 + lh * 4 + r;
        int col = n0 + wn + j * 16 + l15;
        ob[(size_t)row * S_ + col] = acc[i][j][r];
      }
}

extern "C" void kernel_launch(void* const* d_in, const int* in_sizes, int n_in,
                              void* d_out, int out_size, void* d_ws, size_t ws_size,
                              hipStream_t stream) {
  const float* x = (const float*)d_in[0];
  const float* wqkv = (const float*)d_in[1];
  const float* wdw = (const float*)d_in[2];
  const float* wproj = (const float*)d_in[3];
  const float* temp = (const float*)d_in[4];
  float* out = (float*)d_out;

  char* ws = (char*)d_ws;
  size_t off = 0;
  auto alloc = [&](size_t bytes) -> void* {
    void* p = ws + off;
    off += (bytes + 255) & ~(size_t)255;
    return p;
  };
  unsigned short* wq_hi    = (unsigned short*)alloc((size_t)O3_ * C_ * 2);
  unsigned short* wq_lo    = (unsigned short*)alloc((size_t)O3_ * C_ * 2);
  unsigned short* wproj_bf = (unsigned short*)alloc((size_t)C_ * C_ * 2);
  float*          raw      = (float*)alloc((size_t)B_ * O3_ * S_ * 4);
  unsigned short* q_hi     = (unsigned short*)alloc((size_t)B_ * H_ * S_ * 32 * 2);
  unsigned short* q_lo     = (unsigned short*)alloc((size_t)B_ * H_ * S_ * 32 * 2);
  unsigned short* k_hi     = (unsigned short*)alloc((size_t)B_ * H_ * S_ * 32 * 2);
  unsigned short* k_lo     = (unsigned short*)alloc((size_t)B_ * H_ * S_ * 32 * 2);
  unsigned short* vt       = (unsigned short*)alloc((size_t)B_ * H_ * 32 * S_ * 2);
  unsigned short* ao       = (unsigned short*)raw; // alias (raw dead after k_dwnorm)

  (void)hipFuncSetAttribute(reinterpret_cast<const void*>(k_attn),
                            hipFuncAttributeMaxDynamicSharedMemorySize, (int)K3_LDS_BYTES);

  k_convw<<<dim3((O3_ * C_ + 255) / 256), dim3(256), 0, stream>>>(wqkv, wproj, wq_hi, wq_lo, wproj_bf);
  k_qkv<<<dim3(S_ / 64, O3_ / 64, B_), dim3(256), 0, stream>>>(wq_hi, wq_lo, x, raw);
  k_dwnorm<<<dim3(S_ / 32, H_, B_), dim3(256), 0, stream>>>(raw, wdw, temp, q_hi, q_lo, k_hi, k_lo, vt);
  k_attn<<<dim3(B_ * H_ * (S_ / QT)), dim3(1024), K3_LDS_BYTES, stream>>>(q_hi, q_lo, k_hi, k_lo, vt, ao);
  k_proj<<<dim3(S_ / 64, C_ / 64, B_), dim3(256), 0, stream>>>(wproj_bf, ao, out);
}

// Round 14
// 247.195 us; speedup vs baseline: 1.2394x; 1.0195x over previous
//
#include <hip/hip_runtime.h>
#include <math.h>

typedef __attribute__((ext_vector_type(8))) short short8;
typedef __attribute__((ext_vector_type(4))) float f32x4;
typedef __attribute__((ext_vector_type(2))) float f32x2;
typedef __attribute__((ext_vector_type(2))) unsigned int uint2v;

#define DEV __device__ __forceinline__

static constexpr int B_ = 4, C_ = 256, S_ = 2048, H_ = 8, O3_ = 768;
static constexpr int TOPK = 512;
static constexpr int QT = 16;           // q rows per workgroup in attention
static constexpr int QCOLS = 512;       // score cols per quarter pass
static constexpr int QSTR = 516;        // fp32 score row stride (quarter buffer)
static constexpr int QBUF = 16 * QSTR;  // floats per quarter buffer (8256)
static constexpr int PSTH = 1024;       // bf16 P half row stride
static constexpr int P1OFF = 2 * QBUF;  // ushort offset of P1 (64-aligned -> swizzle bijective)
static constexpr size_t K3_LDS_BYTES = (size_t)2 * QBUF * 4;  // 66048 B -> 2 WGs/CU

// k_qkvf geometry
static constexpr int XQSTR = 40;        // staging row stride (ushorts); 80B, 16B-aligned, bank-spread
static constexpr int NROWS = 80;        // staged s-rows (padded; [0,66) valid)
static constexpr int RSTR = 85;         // relay row stride (floats); 4*85 mod 32 = 20 -> 8-bank spread

DEV unsigned cvt_pk_bf16(float a, float b) {
  unsigned r;
  asm("v_cvt_pk_bf16_f32 %0, %1, %2" : "=v"(r) : "v"(a), "v"(b));
  return r;  // lo16 = bf16(a), hi16 = bf16(b)
}
DEV unsigned short f2bf1(float f) { return (unsigned short)(cvt_pk_bf16(f, f) & 0xFFFFu); }
DEV void hilo(float f, unsigned short& h, unsigned short& l) {
  unsigned p = cvt_pk_bf16(f, f);
  h = (unsigned short)p;
  float r = f - __uint_as_float(p << 16);
  l = (unsigned short)(cvt_pk_bf16(r, r) & 0xFFFFu);
}

// ---------------- K0a: weights -> bf16 hi/lo (qkv), bf16 (proj) ----------------
__global__ void k_convw(const float* __restrict__ wqkv, const float* __restrict__ wproj,
                        unsigned short* __restrict__ wq_hi, unsigned short* __restrict__ wq_lo,
                        unsigned short* __restrict__ wproj_bf) {
  int i = blockIdx.x * 256 + threadIdx.x;
  if (i < O3_ * C_) {
    unsigned short h, l;
    hilo(wqkv[i], h, l);
    wq_hi[i] = h;
    wq_lo[i] = l;
  }
  if (i < C_ * C_) wproj_bf[i] = f2bf1(wproj[i]);
}

// ---------------- K1: fused qkv GEMM + depthwise conv + l2norm + hilo split ----------------
// Grid (S/64, H, B), 512 thr (8 waves). Per WG: head h's 96 rows (q,k,v x 32d) over 66 s-cols
// (64 outputs + conv halo). x staged transposed per K-step (double buffer, zero-padded edges);
// raw kept in LDS [96][RSTR]; epilogue = conv3 + l2norm + temperature + packed hilo stores.
__global__ __launch_bounds__(512) void k_qkvf(const unsigned short* __restrict__ w_hi,
                                              const unsigned short* __restrict__ w_lo,
                                              const float* __restrict__ x,
                                              const float* __restrict__ wdw,
                                              const float* __restrict__ temp,
                                              unsigned short* __restrict__ q_hi,
                                              unsigned short* __restrict__ q_lo,
                                              unsigned short* __restrict__ k_hi,
                                              unsigned short* __restrict__ k_lo,
                                              unsigned short* __restrict__ vt) {
  __shared__ unsigned short xh[2][NROWS * XQSTR];  // 2 x 6400 B
  __shared__ unsigned short xl[2][NROWS * XQSTR];
  __shared__ float raw[96 * RSTR];                 // 32640 B
  int n0 = blockIdx.x * 64;
  int h = blockIdx.y;
  int b = blockIdx.z;
  int tid = threadIdx.x, lane = tid & 63, wv = tid >> 6;
  int l15 = lane & 15, lh = lane >> 4;
  const float* xb = x + (size_t)b * C_ * S_;

  // stage K-step tile: c in [k0,k0+32), s-rows [0,66) = s in [n0-1, n0+65), zero at edges
  auto stage = [&](int ks, int bufi) {
    int k0 = ks * 32;
    for (int i = tid; i < 66 * 32; i += 512) {
      int kk = i / 66;
      int sr = i - kk * 66;
      int s = n0 - 1 + sr;
      float f = (s >= 0 && s < S_) ? xb[(size_t)(k0 + kk) * S_ + s] : 0.f;
      unsigned short hh, ll;
      hilo(f, hh, ll);
      xh[bufi][sr * XQSTR + kk] = hh;
      xl[bufi][sr * XQSTR + kk] = ll;
    }
  };

  // wave wv<6 owns M-tile wv: rows obase..obase+15
  int mt = wv;
  int obase = (mt >> 1) * 256 + h * 32 + (mt & 1) * 16;  // q/k/v channel block
  f32x4 acc[5] = {};

  stage(0, 0);
  for (int ks = 0; ks < 8; ++ks) {
    __syncthreads();  // buf ks&1 staged; prior buffer's reads fenced
    if (ks < 7) stage(ks + 1, (ks + 1) & 1);
    if (wv < 6) {
      int kk = lh * 8;
      short8 ahf = *(const short8*)(w_hi + (size_t)(obase + l15) * C_ + ks * 32 + kk);
      short8 alf = *(const short8*)(w_lo + (size_t)(obase + l15) * C_ + ks * 32 + kk);
#pragma unroll
      for (int n = 0; n < 5; ++n) {
        const unsigned short* bh_ = &xh[ks & 1][(n * 16 + l15) * XQSTR + kk];
        const unsigned short* bl_ = &xl[ks & 1][(n * 16 + l15) * XQSTR + kk];
        short8 bh = *(const short8*)bh_;
        short8 bl = *(const short8*)bl_;
        acc[n] = __builtin_amdgcn_mfma_f32_16x16x32_bf16(ahf, bh, acc[n], 0, 0, 0);
        acc[n] = __builtin_amdgcn_mfma_f32_16x16x32_bf16(ahf, bl, acc[n], 0, 0, 0);
        acc[n] = __builtin_amdgcn_mfma_f32_16x16x32_bf16(alf, bh, acc[n], 0, 0, 0);
      }
    }
  }
  __syncthreads();  // all MFMA reads of staging done (staging regions now dead)
  if (wv < 6) {
#pragma unroll
    for (int n = 0; n < 5; ++n)
#pragma unroll
      for (int r = 0; r < 4; ++r)
        raw[(mt * 16 + lh * 4 + r) * RSTR + n * 16 + l15] = acc[n][r];
  }
  __syncthreads();  // raw tile complete

  // ---- epilogue: conv3 + l2norm + temperature + hilo stores (mirrors old k_dwnorm) ----
  {
    int s_loc = tid >> 3;   // 0..63
    int dg = tid & 7;       // d-group (4 d's)
    int s = n0 + s_loc;
    float tph = temp[h];
    size_t bh_ = (size_t)(b * H_ + h);
    float qv[4], kv[4], vv[4];
    float sq = 0.f, sk = 0.f;
#pragma unroll
    for (int dd = 0; dd < 4; ++dd) {
      int d = dg * 4 + dd;
      int oq = h * 32 + d;
      const float* wq = wdw + oq * 3;
      const float* wk = wdw + (oq + 256) * 3;
      const float* wvv = wdw + (oq + 512) * 3;
      const float* rq = &raw[d * RSTR + s_loc];
      const float* rk = &raw[(32 + d) * RSTR + s_loc];
      const float* rv = &raw[(64 + d) * RSTR + s_loc];
      float q = wq[0] * rq[0] + wq[1] * rq[1] + wq[2] * rq[2];
      float k = wk[0] * rk[0] + wk[1] * rk[1] + wk[2] * rk[2];
      float v = wvv[0] * rv[0] + wvv[1] * rv[1] + wvv[2] * rv[2];
      qv[dd] = q; sq += q * q;
      kv[dd] = k; sk += k * k;
      vv[dd] = v;
    }
#pragma unroll
    for (int m = 1; m < 8; m <<= 1) {
      sq += __shfl_xor(sq, m);
      sk += __shfl_xor(sk, m);
    }
    float iq = tph / fmaxf(sqrtf(sq), 1e-12f);
    float ik = 1.f / fmaxf(sqrtf(sk), 1e-12f);
    size_t base = (bh_ * S_ + s) * 32 + dg * 4;

    float q0 = qv[0] * iq, q1 = qv[1] * iq, q2 = qv[2] * iq, q3 = qv[3] * iq;
    unsigned qh01 = cvt_pk_bf16(q0, q1), qh23 = cvt_pk_bf16(q2, q3);
    *(uint2v*)(q_hi + base) = uint2v{qh01, qh23};
    float ql0 = q0 - __uint_as_float(qh01 << 16);
    float ql1 = q1 - __uint_as_float(qh01 & 0xFFFF0000u);
    float ql2 = q2 - __uint_as_float(qh23 << 16);
    float ql3 = q3 - __uint_as_float(qh23 & 0xFFFF0000u);
    *(uint2v*)(q_lo + base) = uint2v{cvt_pk_bf16(ql0, ql1), cvt_pk_bf16(ql2, ql3)};

    float k0 = kv[0] * ik, k1 = kv[1] * ik, k2 = kv[2] * ik, k3 = kv[3] * ik;
    unsigned kh01 = cvt_pk_bf16(k0, k1), kh23 = cvt_pk_bf16(k2, k3);
    *(uint2v*)(k_hi + base) = uint2v{kh01, kh23};
    float kl0 = k0 - __uint_as_float(kh01 << 16);
    float kl1 = k1 - __uint_as_float(kh01 & 0xFFFF0000u);
    float kl2 = k2 - __uint_as_float(kh23 << 16);
    float kl3 = k3 - __uint_as_float(kh23 & 0xFFFF0000u);
    *(uint2v*)(k_lo + base) = uint2v{cvt_pk_bf16(kl0, kl1), cvt_pk_bf16(kl2, kl3)};

#pragma unroll
    for (int dd = 0; dd < 4; ++dd) {
      int d = dg * 4 + dd;
      vt[(bh_ * 32 + d) * S_ + s] = f2bf1(vv[dd]);
    }
  }
}

// ---------------- K3: fused QK^T (split-bf16) -> exact top-512 -> softmax -> PV ----------------
// (identical to R13)
__global__ __launch_bounds__(1024, 8) void k_attn(const unsigned short* __restrict__ q_hi,
                                                  const unsigned short* __restrict__ q_lo,
                                                  const unsigned short* __restrict__ k_hi,
                                                  const unsigned short* __restrict__ k_lo,
                                                  const unsigned short* __restrict__ vt,
                                                  unsigned short* __restrict__ ao) {
  extern __shared__ float smem[];
  __shared__ float is_arr[QT];
  unsigned short* Pb = (unsigned short*)smem;
  float* red = smem;
  int bid = blockIdx.x;
  int tile = bid & 127;
  int bh = bid >> 7;
  int q0 = tile * QT;
  int tid = threadIdx.x, lane = tid & 63, wv = tid >> 6;
  int l15 = lane & 15, lh = lane >> 4;
  const unsigned short* vb = vt + (size_t)bh * 32 * S_;

  size_t qoff = ((size_t)bh * S_ + q0 + l15) * 32 + lh * 8;
  short8 ah = *(const short8*)(q_hi + qoff);
  short8 al = *(const short8*)(q_lo + qoff);
  size_t kbase = (size_t)bh * S_ * 32;

  float v[32];

  short8 kh0, kl0, kh1, kl1;
  {
    const unsigned short* kp = k_hi + kbase + (size_t)(wv * 32 + l15) * 32 + lh * 8;
    const unsigned short* lp = k_lo + kbase + (size_t)(wv * 32 + l15) * 32 + lh * 8;
    kh0 = *(const short8*)(kp);       kl0 = *(const short8*)(lp);
    kh1 = *(const short8*)(kp + 512); kl1 = *(const short8*)(lp + 512);
  }
#pragma unroll
  for (int qq = 0; qq < 4; ++qq) {
    float* buf = smem + (qq & 1) * QBUF;
    {
      f32x4 d0 = {}, d1 = {};
      __builtin_amdgcn_s_setprio(1);
      d0 = __builtin_amdgcn_mfma_f32_16x16x32_bf16(ah, kh0, d0, 0, 0, 0);
      d0 = __builtin_amdgcn_mfma_f32_16x16x32_bf16(ah, kl0, d0, 0, 0, 0);
      d0 = __builtin_amdgcn_mfma_f32_16x16x32_bf16(al, kh0, d0, 0, 0, 0);
      d1 = __builtin_amdgcn_mfma_f32_16x16x32_bf16(ah, kh1, d1, 0, 0, 0);
      d1 = __builtin_amdgcn_mfma_f32_16x16x32_bf16(ah, kl1, d1, 0, 0, 0);
      d1 = __builtin_amdgcn_mfma_f32_16x16x32_bf16(al, kh1, d1, 0, 0, 0);
      __builtin_amdgcn_s_setprio(0);
      int tloc = wv * 32 + l15;
#pragma unroll
      for (int r = 0; r < 4; ++r) {
        buf[(lh * 4 + r) * QSTR + tloc] = d0[r];
        buf[(lh * 4 + r) * QSTR + tloc + 16] = d1[r];
      }
      if (qq < 3) {
        int colg = (qq + 1) * QCOLS + wv * 32;
        const unsigned short* kp = k_hi + kbase + (size_t)(colg + l15) * 32 + lh * 8;
        const unsigned short* lp = k_lo + kbase + (size_t)(colg + l15) * 32 + lh * 8;
        kh0 = *(const short8*)(kp);       kl0 = *(const short8*)(lp);
        kh1 = *(const short8*)(kp + 512); kl1 = *(const short8*)(lp + 512);
      }
    }
    __syncthreads();
#pragma unroll
    for (int kk2 = 0; kk2 < 4; ++kk2) {
      f32x2 pr = *(const f32x2*)&buf[wv * QSTR + kk2 * 128 + 2 * lane];
      v[qq * 8 + kk2 * 2] = pr[0];
      v[qq * 8 + kk2 * 2 + 1] = pr[1];
    }
  }

  {
    float vmax = v[0], vmin = v[0], sum = 0.f, sqs = 0.f;
#pragma unroll
    for (int j = 0; j < 32; ++j) {
      vmax = fmaxf(vmax, v[j]); vmin = fminf(vmin, v[j]);
      sum += v[j]; sqs = fmaf(v[j], v[j], sqs);
    }
#pragma unroll
    for (int m = 1; m < 64; m <<= 1) {
      vmax = fmaxf(vmax, __shfl_xor(vmax, m));
      vmin = fminf(vmin, __shfl_xor(vmin, m));
      sum += __shfl_xor(sum, m);
      sqs += __shfl_xor(sqs, m);
    }
    float mu = sum * (1.f / 2048.f);
    float sig = sqrtf(fmaxf(sqs * (1.f / 2048.f) - mu * mu, 0.f));

    float vlo = vmin - 1e-3f, vhi = vmax;
    float flo = 1536.f, fhi = -512.f;
    int chi = 0;
    float T = vhi;
    bool exact = false;
    int lastside = 0;
    float piv = mu + 0.67449f * sig;
    if (!(piv > vlo && piv < vhi)) piv = 0.5f * (vlo + vhi);
    for (int it = 0; it < 32; ++it) {
      int c = 0;
#pragma unroll
      for (int j = 0; j < 32; ++j)
        c += (int)__popcll(__ballot(v[j] > piv));
      if (c == TOPK) { T = piv; exact = true; break; }
      if (c > TOPK) {
        if (lastside == 1) fhi *= 0.5f;
        vlo = piv; flo = (float)(c - TOPK); lastside = 1;
      } else {
        if (lastside == -1) flo *= 0.5f;
        vhi = piv; fhi = (float)(c - TOPK); chi = c; lastside = -1;
      }
      float npiv;
      if (it == 0 && sig > 1e-20f) {
        float z = (piv - mu) / sig;
        float dens = 0.398942f * __expf(-0.5f * z * z) * (2048.f / sig);
        npiv = piv + (float)(c - TOPK) / fmaxf(dens, 1e-6f);
      } else {
        npiv = vhi - fhi * (vhi - vlo) / (fhi - flo);
      }
      if (!(npiv > vlo && npiv < vhi)) npiv = 0.5f * (vlo + vhi);
      if (!(npiv > vlo && npiv < vhi)) break;
      piv = npiv;
    }
    int cntGT = exact ? TOPK : chi;
    if (!exact) T = vhi;

    unsigned selbits = 0;
#pragma unroll
    for (int j = 0; j < 32; ++j)
      if (v[j] > T) selbits |= (1u << j);
    int need = TOPK - cntGT;
    if (need > 0) {
      int base = 0;
      unsigned long long lmask = (lane == 0) ? 0ull : (~0ull >> (64 - lane));
#pragma unroll
      for (int k = 0; k < 16; ++k) {
        bool t0 = (v[2 * k] == T), t1 = (v[2 * k + 1] == T);
        unsigned long long m0 = __ballot(t0);
        unsigned long long m1 = __ballot(t1);
        int before = base + (int)__popcll(m0 & lmask) + (int)__popcll(m1 & lmask);
        int r0 = before;
        int r1 = before + (t0 ? 1 : 0);
        if (t0 && r0 < need) selbits |= (1u << (2 * k));
        if (t1 && r1 < need) selbits |= (1u << (2 * k + 1));
        base += (int)__popcll(m0) + (int)__popcll(m1);
      }
    }

    float ssum = 0.f;
#pragma unroll
    for (int j = 0; j < 32; ++j) {
      float e = ((selbits >> j) & 1u) ? __expf(v[j] - vmax) : 0.f;
      v[j] = e;
      ssum += e;
    }
#pragma unroll
    for (int m = 1; m < 64; m <<= 1) ssum += __shfl_xor(ssum, m);
    if (lane == 0) is_arr[wv] = 1.f / ssum;
  }

  f32x4 acc0 = {}, acc1 = {};
  int swz_w = (wv & 7) << 3;
  int swz_r = (l15 & 7) << 3;
#pragma unroll
  for (int kk = 0; kk < 8; ++kk) {
    int lc = (kk >> 2) * 512 + (kk & 3) * 128 + 2 * lane;
    unsigned pk = cvt_pk_bf16(v[2 * kk], v[2 * kk + 1]);
    *(unsigned*)&Pb[(wv * PSTH + lc) ^ swz_w] = pk;
  }
  __syncthreads();
  {
#pragma unroll
    for (int kk = 0; kk < 8; ++kk) {
      int lc = (kk >> 2) * 512 + (kk & 3) * 128 + 2 * lane;
      unsigned pk = cvt_pk_bf16(v[16 + 2 * kk], v[16 + 2 * kk + 1]);
      *(unsigned*)&Pb[P1OFF + ((wv * PSTH + lc) ^ swz_w)] = pk;
    }
    const unsigned short* v0p = vb + (size_t)l15 * S_ + wv * 64 + lh * 8;
    const unsigned short* v1p = v0p + 16 * S_;
#pragma unroll
    for (int kt = 0; kt < 2; ++kt) {
      int lc = wv * 64 + kt * 32 + lh * 8;
      short8 a = *(const short8*)(Pb + ((l15 * PSTH + lc) ^ swz_r));
      short8 b0 = *(const short8*)(v0p + kt * 32);
      short8 b1 = *(const short8*)(v1p + kt * 32);
      __builtin_amdgcn_s_setprio(1);
      acc0 = __builtin_amdgcn_mfma_f32_16x16x32_bf16(a, b0, acc0, 0, 0, 0);
      acc1 = __builtin_amdgcn_mfma_f32_16x16x32_bf16(a, b1, acc1, 0, 0, 0);
      __builtin_amdgcn_s_setprio(0);
    }
  }
  __syncthreads();
  {
    const unsigned short* v0p = vb + (size_t)l15 * S_ + 1024 + wv * 64 + lh * 8;
    const unsigned short* v1p = v0p + 16 * S_;
#pragma unroll
    for (int kt = 0; kt < 2; ++kt) {
      int lc = wv * 64 + kt * 32 + lh * 8;
      short8 a = *(const short8*)(Pb + P1OFF + ((l15 * PSTH + lc) ^ swz_r));
      short8 b0 = *(const short8*)(v0p + kt * 32);
      short8 b1 = *(const short8*)(v1p + kt * 32);
      __builtin_amdgcn_s_setprio(1);
      acc0 = __builtin_amdgcn_mfma_f32_16x16x32_bf16(a, b0, acc0, 0, 0, 0);
      acc1 = __builtin_amdgcn_mfma_f32_16x16x32_bf16(a, b1, acc1, 0, 0, 0);
      __builtin_amdgcn_s_setprio(0);
    }
  }
  __syncthreads();

#pragma unroll
  for (int r = 0; r < 4; ++r) {
    red[wv * 529 + (lh * 4 + r) * 33 + l15] = acc0[r];
    red[wv * 529 + (lh * 4 + r) * 33 + 16 + l15] = acc1[r];
  }
  __syncthreads();
  if (tid < 512) {
    int row = tid >> 5, d = tid & 31;
    float s = 0.f;
#pragma unroll
    for (int w = 0; w < 16; ++w) s += red[w * 529 + row * 33 + d];
    s *= is_arr[row];
    ao[((size_t)bh * S_ + q0 + row) * 32 + d] = f2bf1(s);
  }
}

// ---------------- K4: output projection ----------------
__global__ __launch_bounds__(256) void k_proj(const unsigned short* __restrict__ wbf,
                                              const unsigned short* __restrict__ ao,
                                              float* __restrict__ out) {
  int b = blockIdx.z;
  int m0 = blockIdx.y * 64, n0 = blockIdx.x * 64;
  int tid = threadIdx.x, lane = tid & 63, wid = tid >> 6;
  int l15 = lane & 15, lh = lane >> 4;
  int wm = (wid >> 1) * 32, wn = (wid & 1) * 32;
  const unsigned short* aob = ao + (size_t)b * H_ * S_ * 32;
  f32x4 acc[2][2] = {};
  int mA = m0 + wm + l15;
  int nB = n0 + wn + l15;
  for (int k0 = 0; k0 < C_; k0 += 32) {
    int kk = k0 + lh * 8;
    int hh = kk >> 5;
    int dd = kk & 31;
    short8 a0 = *(const short8*)(wbf + (size_t)mA * C_ + kk);
    short8 a1 = *(const short8*)(wbf + (size_t)(mA + 16) * C_ + kk);
    short8 b0 = *(const short8*)(aob + ((size_t)hh * S_ + nB) * 32 + dd);
    short8 b1 = *(const short8*)(aob + ((size_t)hh * S_ + nB + 16) * 32 + dd);
    acc[0][0] = __builtin_amdgcn_mfma_f32_16x16x32_bf16(a0, b0, acc[0][0], 0, 0, 0);
    acc[0][1] = __builtin_amdgcn_mfma_f32_16x16x32_bf16(a0, b1, acc[0][1], 0, 0, 0);
    acc[1][0] = __builtin_amdgcn_mfma_f32_16x16x32_bf16(a1, b0, acc[1][0], 0, 0, 0);
    acc[1][1] = __builtin_amdgcn_mfma_f32_16x16x32_bf16(a1, b1, acc[1][1], 0, 0, 0);
  }
  float* ob = out + (size_t)b * C_ * S_;
#pragma unroll
  for (int i = 0; i < 2; ++i)
#pragma unroll
    for (int j = 0; j < 2; ++j)
#pragma unroll
      for (int r = 0; r < 4; ++r) {
        int row = m0 + wm + i * 16 + lh * 4 + r;
        int col = n0 + wn + j * 16 + l15;
        ob[(size_t)row * S_ + col] = acc[i][j][r];
      }
}

extern "C" void kernel_launch(void* const* d_in, const int* in_sizes, int n_in,
                              void* d_out, int out_size, void* d_ws, size_t ws_size,
                              hipStream_t stream) {
  const float* x = (const float*)d_in[0];
  const float* wqkv = (const float*)d_in[1];
  const float* wdw = (const float*)d_in[2];
  const float* wproj = (const float*)d_in[3];
  const float* temp = (const float*)d_in[4];
  float* out = (float*)d_out;

  char* ws = (char*)d_ws;
  size_t off = 0;
  auto alloc = [&](size_t bytes) -> void* {
    void* p = ws + off;
    off += (bytes + 255) & ~(size_t)255;
    return p;
  };
  unsigned short* wq_hi    = (unsigned short*)alloc((size_t)O3_ * C_ * 2);
  unsigned short* wq_lo    = (unsigned short*)alloc((size_t)O3_ * C_ * 2);
  unsigned short* wproj_bf = (unsigned short*)alloc((size_t)C_ * C_ * 2);
  unsigned short* q_hi     = (unsigned short*)alloc((size_t)B_ * H_ * S_ * 32 * 2);
  unsigned short* q_lo     = (unsigned short*)alloc((size_t)B_ * H_ * S_ * 32 * 2);
  unsigned short* k_hi     = (unsigned short*)alloc((size_t)B_ * H_ * S_ * 32 * 2);
  unsigned short* k_lo     = (unsigned short*)alloc((size_t)B_ * H_ * S_ * 32 * 2);
  unsigned short* vt       = (unsigned short*)alloc((size_t)B_ * H_ * 32 * S_ * 2);
  unsigned short* ao       = (unsigned short*)alloc((size_t)B_ * H_ * S_ * 32 * 2);

  (void)hipFuncSetAttribute(reinterpret_cast<const void*>(k_attn),
                            hipFuncAttributeMaxDynamicSharedMemorySize, (int)K3_LDS_BYTES);

  k_convw<<<dim3((O3_ * C_ + 255) / 256), dim3(256), 0, stream>>>(wqkv, wproj, wq_hi, wq_lo, wproj_bf);
  k_qkvf<<<dim3(S_ / 64, H_, B_), dim3(512), 0, stream>>>(wq_hi, wq_lo, x, wdw, temp,
                                                          q_hi, q_lo, k_hi, k_lo, vt);
  k_attn<<<dim3(B_ * H_ * (S_ / QT)), dim3(1024), K3_LDS_BYTES, stream>>>(q_hi, q_lo, k_hi, k_lo, vt, ao);
  k_proj<<<dim3(S_ / 64, C_ / 64, B_), dim3(256), 0, stream>>>(wproj_bf, ao, out);
}

// Round 15
// 241.089 us; speedup vs baseline: 1.2708x; 1.0253x over previous
//
#include <hip/hip_runtime.h>
#include <math.h>

typedef __attribute__((ext_vector_type(8))) short short8;
typedef __attribute__((ext_vector_type(4))) float f32x4;
typedef __attribute__((ext_vector_type(2))) float f32x2;
typedef __attribute__((ext_vector_type(2))) unsigned int uint2v;

#define DEV __device__ __forceinline__

static constexpr int B_ = 4, C_ = 256, S_ = 2048, H_ = 8, O3_ = 768;
static constexpr int TOPK = 512;
static constexpr int QT = 16;           // q rows per workgroup in attention
static constexpr int QCOLS = 512;       // score cols per quarter pass
static constexpr int QSTR = 516;        // fp32 score row stride (quarter buffer)
static constexpr int QBUF = 16 * QSTR;  // floats per quarter buffer (8256)
static constexpr int PSTH = 1024;       // bf16 P half row stride
static constexpr int P1OFF = 2 * QBUF;  // ushort offset of P1 (64-aligned -> swizzle bijective)
static constexpr size_t K3_LDS_BYTES = (size_t)2 * QBUF * 4;  // 66048 B -> 2 WGs/CU

// k_qkvf geometry
static constexpr int XQSTR = 40;        // staging row stride (ushorts); 80B, 16B-aligned, bank-spread
static constexpr int NROWS = 80;        // staged s-rows (padded; [0,66) valid)
static constexpr int RSTR = 85;         // relay row stride (floats)

DEV unsigned cvt_pk_bf16(float a, float b) {
  unsigned r;
  asm("v_cvt_pk_bf16_f32 %0, %1, %2" : "=v"(r) : "v"(a), "v"(b));
  return r;  // lo16 = bf16(a), hi16 = bf16(b)
}
DEV unsigned short f2bf1(float f) { return (unsigned short)(cvt_pk_bf16(f, f) & 0xFFFFu); }
DEV void hilo(float f, unsigned short& h, unsigned short& l) {
  unsigned p = cvt_pk_bf16(f, f);
  h = (unsigned short)p;
  float r = f - __uint_as_float(p << 16);
  l = (unsigned short)(cvt_pk_bf16(r, r) & 0xFFFFu);
}

// ---------------- K0a: weights -> bf16 hi/lo (qkv), bf16 (proj) ----------------
__global__ void k_convw(const float* __restrict__ wqkv, const float* __restrict__ wproj,
                        unsigned short* __restrict__ wq_hi, unsigned short* __restrict__ wq_lo,
                        unsigned short* __restrict__ wproj_bf) {
  int i = blockIdx.x * 256 + threadIdx.x;
  if (i < O3_ * C_) {
    unsigned short h, l;
    hilo(wqkv[i], h, l);
    wq_hi[i] = h;
    wq_lo[i] = l;
  }
  if (i < C_ * C_) wproj_bf[i] = f2bf1(wproj[i]);
}

// ---------------- K1: fused qkv GEMM + depthwise conv + l2norm + hilo split ----------------
// Grid (S/64, H, B), 512 thr (8 waves). Division-free staging: thread t owns channel t>>4;
// its 16-thread group covers 66 s-rows in 5 predicated steps.
__global__ __launch_bounds__(512) void k_qkvf(const unsigned short* __restrict__ w_hi,
                                              const unsigned short* __restrict__ w_lo,
                                              const float* __restrict__ x,
                                              const float* __restrict__ wdw,
                                              const float* __restrict__ temp,
                                              unsigned short* __restrict__ q_hi,
                                              unsigned short* __restrict__ q_lo,
                                              unsigned short* __restrict__ k_hi,
                                              unsigned short* __restrict__ k_lo,
                                              unsigned short* __restrict__ vt) {
  __shared__ unsigned short xh[2][NROWS * XQSTR];  // 2 x 6400 B
  __shared__ unsigned short xl[2][NROWS * XQSTR];
  __shared__ float raw[96 * RSTR];                 // 32640 B
  int n0 = blockIdx.x * 64;
  int h = blockIdx.y;
  int b = blockIdx.z;
  int tid = threadIdx.x, lane = tid & 63, wv = tid >> 6;
  int l15 = lane & 15, lh = lane >> 4;
  const float* xb = x + (size_t)b * C_ * S_;

  // staging roles (division-free): channel kc = tid>>4 (0..31), s-group base = tid&15
  int kc = tid >> 4;
  int sg = tid & 15;
  // stage K-step tile: c in [k0,k0+32), s-rows [0,66) = s in [n0-1, n0+65), zero at edges
  auto stage = [&](int ks, int bufi) {
    int k0 = ks * 32;
    const float* xc = xb + (size_t)(k0 + kc) * S_ + n0 - 1;
#pragma unroll
    for (int j = 0; j < 5; ++j) {
      int sr = sg + 16 * j;
      if (sr < 66) {
        int s = n0 - 1 + sr;
        float f = (s >= 0 && s < S_) ? xc[sr] : 0.f;
        unsigned short hh, ll;
        hilo(f, hh, ll);
        xh[bufi][sr * XQSTR + kc] = hh;
        xl[bufi][sr * XQSTR + kc] = ll;
      }
    }
  };

  // wave wv<6 owns M-tile wv: rows obase..obase+15
  int mt = wv;
  int obase = (mt >> 1) * 256 + h * 32 + (mt & 1) * 16;  // q/k/v channel block
  f32x4 acc[5] = {};

  stage(0, 0);
  for (int ks = 0; ks < 8; ++ks) {
    __syncthreads();  // buf ks&1 staged; prior buffer's reads fenced
    if (ks < 7) stage(ks + 1, (ks + 1) & 1);
    if (wv < 6) {
      int kk = lh * 8;
      short8 ahf = *(const short8*)(w_hi + (size_t)(obase + l15) * C_ + ks * 32 + kk);
      short8 alf = *(const short8*)(w_lo + (size_t)(obase + l15) * C_ + ks * 32 + kk);
#pragma unroll
      for (int n = 0; n < 5; ++n) {
        const unsigned short* bh_ = &xh[ks & 1][(n * 16 + l15) * XQSTR + kk];
        const unsigned short* bl_ = &xl[ks & 1][(n * 16 + l15) * XQSTR + kk];
        short8 bh = *(const short8*)bh_;
        short8 bl = *(const short8*)bl_;
        acc[n] = __builtin_amdgcn_mfma_f32_16x16x32_bf16(ahf, bh, acc[n], 0, 0, 0);
        acc[n] = __builtin_amdgcn_mfma_f32_16x16x32_bf16(ahf, bl, acc[n], 0, 0, 0);
        acc[n] = __builtin_amdgcn_mfma_f32_16x16x32_bf16(alf, bh, acc[n], 0, 0, 0);
      }
    }
  }
  __syncthreads();  // all MFMA reads of staging done
  if (wv < 6) {
#pragma unroll
    for (int n = 0; n < 5; ++n)
#pragma unroll
      for (int r = 0; r < 4; ++r)
        raw[(mt * 16 + lh * 4 + r) * RSTR + n * 16 + l15] = acc[n][r];
  }
  __syncthreads();  // raw tile complete

  // ---- epilogue: conv3 + l2norm + temperature + hilo stores ----
  {
    int s_loc = tid >> 3;   // 0..63
    int dg = tid & 7;       // d-group (4 d's)
    int s = n0 + s_loc;
    float tph = temp[h];
    size_t bh_ = (size_t)(b * H_ + h);
    float qv[4], kv[4], vv[4];
    float sq = 0.f, sk = 0.f;
#pragma unroll
    for (int dd = 0; dd < 4; ++dd) {
      int d = dg * 4 + dd;
      int oq = h * 32 + d;
      const float* wq = wdw + oq * 3;
      const float* wk = wdw + (oq + 256) * 3;
      const float* wvv = wdw + (oq + 512) * 3;
      const float* rq = &raw[d * RSTR + s_loc];
      const float* rk = &raw[(32 + d) * RSTR + s_loc];
      const float* rv = &raw[(64 + d) * RSTR + s_loc];
      float q = wq[0] * rq[0] + wq[1] * rq[1] + wq[2] * rq[2];
      float k = wk[0] * rk[0] + wk[1] * rk[1] + wk[2] * rk[2];
      float v = wvv[0] * rv[0] + wvv[1] * rv[1] + wvv[2] * rv[2];
      qv[dd] = q; sq += q * q;
      kv[dd] = k; sk += k * k;
      vv[dd] = v;
    }
#pragma unroll
    for (int m = 1; m < 8; m <<= 1) {
      sq += __shfl_xor(sq, m);
      sk += __shfl_xor(sk, m);
    }
    float iq = tph / fmaxf(sqrtf(sq), 1e-12f);
    float ik = 1.f / fmaxf(sqrtf(sk), 1e-12f);
    size_t base = (bh_ * S_ + s) * 32 + dg * 4;

    float q0 = qv[0] * iq, q1 = qv[1] * iq, q2 = qv[2] * iq, q3 = qv[3] * iq;
    unsigned qh01 = cvt_pk_bf16(q0, q1), qh23 = cvt_pk_bf16(q2, q3);
    *(uint2v*)(q_hi + base) = uint2v{qh01, qh23};
    float ql0 = q0 - __uint_as_float(qh01 << 16);
    float ql1 = q1 - __uint_as_float(qh01 & 0xFFFF0000u);
    float ql2 = q2 - __uint_as_float(qh23 << 16);
    float ql3 = q3 - __uint_as_float(qh23 & 0xFFFF0000u);
    *(uint2v*)(q_lo + base) = uint2v{cvt_pk_bf16(ql0, ql1), cvt_pk_bf16(ql2, ql3)};

    float k0 = kv[0] * ik, k1 = kv[1] * ik, k2 = kv[2] * ik, k3 = kv[3] * ik;
    unsigned kh01 = cvt_pk_bf16(k0, k1), kh23 = cvt_pk_bf16(k2, k3);
    *(uint2v*)(k_hi + base) = uint2v{kh01, kh23};
    float kl0 = k0 - __uint_as_float(kh01 << 16);
    float kl1 = k1 - __uint_as_float(kh01 & 0xFFFF0000u);
    float kl2 = k2 - __uint_as_float(kh23 << 16);
    float kl3 = k3 - __uint_as_float(kh23 & 0xFFFF0000u);
    *(uint2v*)(k_lo + base) = uint2v{cvt_pk_bf16(kl0, kl1), cvt_pk_bf16(kl2, kl3)};

#pragma unroll
    for (int dd = 0; dd < 4; ++dd) {
      int d = dg * 4 + dd;
      vt[(bh_ * 32 + d) * S_ + s] = f2bf1(vv[dd]);
    }
  }
}

// ---------------- K3: fused QK^T (split-bf16) -> exact top-512 -> softmax -> PV ----------------
// (identical to R13/R14 keeper)
__global__ __launch_bounds__(1024, 8) void k_attn(const unsigned short* __restrict__ q_hi,
                                                  const unsigned short* __restrict__ q_lo,
                                                  const unsigned short* __restrict__ k_hi,
                                                  const unsigned short* __restrict__ k_lo,
                                                  const unsigned short* __restrict__ vt,
                                                  unsigned short* __restrict__ ao) {
  extern __shared__ float smem[];
  __shared__ float is_arr[QT];
  unsigned short* Pb = (unsigned short*)smem;
  float* red = smem;
  int bid = blockIdx.x;
  int tile = bid & 127;
  int bh = bid >> 7;
  int q0 = tile * QT;
  int tid = threadIdx.x, lane = tid & 63, wv = tid >> 6;
  int l15 = lane & 15, lh = lane >> 4;
  const unsigned short* vb = vt + (size_t)bh * 32 * S_;

  size_t qoff = ((size_t)bh * S_ + q0 + l15) * 32 + lh * 8;
  short8 ah = *(const short8*)(q_hi + qoff);
  short8 al = *(const short8*)(q_lo + qoff);
  size_t kbase = (size_t)bh * S_ * 32;

  float v[32];

  short8 kh0, kl0, kh1, kl1;
  {
    const unsigned short* kp = k_hi + kbase + (size_t)(wv * 32 + l15) * 32 + lh * 8;
    const unsigned short* lp = k_lo + kbase + (size_t)(wv * 32 + l15) * 32 + lh * 8;
    kh0 = *(const short8*)(kp);       kl0 = *(const short8*)(lp);
    kh1 = *(const short8*)(kp + 512); kl1 = *(const short8*)(lp + 512);
  }
#pragma unroll
  for (int qq = 0; qq < 4; ++qq) {
    float* buf = smem + (qq & 1) * QBUF;
    {
      f32x4 d0 = {}, d1 = {};
      __builtin_amdgcn_s_setprio(1);
      d0 = __builtin_amdgcn_mfma_f32_16x16x32_bf16(ah, kh0, d0, 0, 0, 0);
      d0 = __builtin_amdgcn_mfma_f32_16x16x32_bf16(ah, kl0, d0, 0, 0, 0);
      d0 = __builtin_amdgcn_mfma_f32_16x16x32_bf16(al, kh0, d0, 0, 0, 0);
      d1 = __builtin_amdgcn_mfma_f32_16x16x32_bf16(ah, kh1, d1, 0, 0, 0);
      d1 = __builtin_amdgcn_mfma_f32_16x16x32_bf16(ah, kl1, d1, 0, 0, 0);
      d1 = __builtin_amdgcn_mfma_f32_16x16x32_bf16(al, kh1, d1, 0, 0, 0);
      __builtin_amdgcn_s_setprio(0);
      int tloc = wv * 32 + l15;
#pragma unroll
      for (int r = 0; r < 4; ++r) {
        buf[(lh * 4 + r) * QSTR + tloc] = d0[r];
        buf[(lh * 4 + r) * QSTR + tloc + 16] = d1[r];
      }
      if (qq < 3) {
        int colg = (qq + 1) * QCOLS + wv * 32;
        const unsigned short* kp = k_hi + kbase + (size_t)(colg + l15) * 32 + lh * 8;
        const unsigned short* lp = k_lo + kbase + (size_t)(colg + l15) * 32 + lh * 8;
        kh0 = *(const short8*)(kp);       kl0 = *(const short8*)(lp);
        kh1 = *(const short8*)(kp + 512); kl1 = *(const short8*)(lp + 512);
      }
    }
    __syncthreads();
#pragma unroll
    for (int kk2 = 0; kk2 < 4; ++kk2) {
      f32x2 pr = *(const f32x2*)&buf[wv * QSTR + kk2 * 128 + 2 * lane];
      v[qq * 8 + kk2 * 2] = pr[0];
      v[qq * 8 + kk2 * 2 + 1] = pr[1];
    }
  }

  {
    float vmax = v[0], vmin = v[0], sum = 0.f, sqs = 0.f;
#pragma unroll
    for (int j = 0; j < 32; ++j) {
      vmax = fmaxf(vmax, v[j]); vmin = fminf(vmin, v[j]);
      sum += v[j]; sqs = fmaf(v[j], v[j], sqs);
    }
#pragma unroll
    for (int m = 1; m < 64; m <<= 1) {
      vmax = fmaxf(vmax, __shfl_xor(vmax, m));
      vmin = fminf(vmin, __shfl_xor(vmin, m));
      sum += __shfl_xor(sum, m);
      sqs += __shfl_xor(sqs, m);
    }
    float mu = sum * (1.f / 2048.f);
    float sig = sqrtf(fmaxf(sqs * (1.f / 2048.f) - mu * mu, 0.f));

    float vlo = vmin - 1e-3f, vhi = vmax;
    float flo = 1536.f, fhi = -512.f;
    int chi = 0;
    float T = vhi;
    bool exact = false;
    int lastside = 0;
    float piv = mu + 0.67449f * sig;
    if (!(piv > vlo && piv < vhi)) piv = 0.5f * (vlo + vhi);
    for (int it = 0; it < 32; ++it) {
      int c = 0;
#pragma unroll
      for (int j = 0; j < 32; ++j)
        c += (int)__popcll(__ballot(v[j] > piv));
      if (c == TOPK) { T = piv; exact = true; break; }
      if (c > TOPK) {
        if (lastside == 1) fhi *= 0.5f;
        vlo = piv; flo = (float)(c - TOPK); lastside = 1;
      } else {
        if (lastside == -1) flo *= 0.5f;
        vhi = piv; fhi = (float)(c - TOPK); chi = c; lastside = -1;
      }
      float npiv;
      if (it == 0 && sig > 1e-20f) {
        float z = (piv - mu) / sig;
        float dens = 0.398942f * __expf(-0.5f * z * z) * (2048.f / sig);
        npiv = piv + (float)(c - TOPK) / fmaxf(dens, 1e-6f);
      } else {
        npiv = vhi - fhi * (vhi - vlo) / (fhi - flo);
      }
      if (!(npiv > vlo && npiv < vhi)) npiv = 0.5f * (vlo + vhi);
      if (!(npiv > vlo && npiv < vhi)) break;
      piv = npiv;
    }
    int cntGT = exact ? TOPK : chi;
    if (!exact) T = vhi;

    unsigned selbits = 0;
#pragma unroll
    for (int j = 0; j < 32; ++j)
      if (v[j] > T) selbits |= (1u << j);
    int need = TOPK - cntGT;
    if (need > 0) {
      int base = 0;
      unsigned long long lmask = (lane == 0) ? 0ull : (~0ull >> (64 - lane));
#pragma unroll
      for (int k = 0; k < 16; ++k) {
        bool t0 = (v[2 * k] == T), t1 = (v[2 * k + 1] == T);
        unsigned long long m0 = __ballot(t0);
        unsigned long long m1 = __ballot(t1);
        int before = base + (int)__popcll(m0 & lmask) + (int)__popcll(m1 & lmask);
        int r0 = before;
        int r1 = before + (t0 ? 1 : 0);
        if (t0 && r0 < need) selbits |= (1u << (2 * k));
        if (t1 && r1 < need) selbits |= (1u << (2 * k + 1));
        base += (int)__popcll(m0) + (int)__popcll(m1);
      }
    }

    float ssum = 0.f;
#pragma unroll
    for (int j = 0; j < 32; ++j) {
      float e = ((selbits >> j) & 1u) ? __expf(v[j] - vmax) : 0.f;
      v[j] = e;
      ssum += e;
    }
#pragma unroll
    for (int m = 1; m < 64; m <<= 1) ssum += __shfl_xor(ssum, m);
    if (lane == 0) is_arr[wv] = 1.f / ssum;
  }

  f32x4 acc0 = {}, acc1 = {};
  int swz_w = (wv & 7) << 3;
  int swz_r = (l15 & 7) << 3;
#pragma unroll
  for (int kk = 0; kk < 8; ++kk) {
    int lc = (kk >> 2) * 512 + (kk & 3) * 128 + 2 * lane;
    unsigned pk = cvt_pk_bf16(v[2 * kk], v[2 * kk + 1]);
    *(unsigned*)&Pb[(wv * PSTH + lc) ^ swz_w] = pk;
  }
  __syncthreads();
  {
#pragma unroll
    for (int kk = 0; kk < 8; ++kk) {
      int lc = (kk >> 2) * 512 + (kk & 3) * 128 + 2 * lane;
      unsigned pk = cvt_pk_bf16(v[16 + 2 * kk], v[16 + 2 * kk + 1]);
      *(unsigned*)&Pb[P1OFF + ((wv * PSTH + lc) ^ swz_w)] = pk;
    }
    const unsigned short* v0p = vb + (size_t)l15 * S_ + wv * 64 + lh * 8;
    const unsigned short* v1p = v0p + 16 * S_;
#pragma unroll
    for (int kt = 0; kt < 2; ++kt) {
      int lc = wv * 64 + kt * 32 + lh * 8;
      short8 a = *(const short8*)(Pb + ((l15 * PSTH + lc) ^ swz_r));
      short8 b0 = *(const short8*)(v0p + kt * 32);
      short8 b1 = *(const short8*)(v1p + kt * 32);
      __builtin_amdgcn_s_setprio(1);
      acc0 = __builtin_amdgcn_mfma_f32_16x16x32_bf16(a, b0, acc0, 0, 0, 0);
      acc1 = __builtin_amdgcn_mfma_f32_16x16x32_bf16(a, b1, acc1, 0, 0, 0);
      __builtin_amdgcn_s_setprio(0);
    }
  }
  __syncthreads();
  {
    const unsigned short* v0p = vb + (size_t)l15 * S_ + 1024 + wv * 64 + lh * 8;
    const unsigned short* v1p = v0p + 16 * S_;
#pragma unroll
    for (int kt = 0; kt < 2; ++kt) {
      int lc = wv * 64 + kt * 32 + lh * 8;
      short8 a = *(const short8*)(Pb + P1OFF + ((l15 * PSTH + lc) ^ swz_r));
      short8 b0 = *(const short8*)(v0p + kt * 32);
      short8 b1 = *(const short8*)(v1p + kt * 32);
      __builtin_amdgcn_s_setprio(1);
      acc0 = __builtin_amdgcn_mfma_f32_16x16x32_bf16(a, b0, acc0, 0, 0, 0);
      acc1 = __builtin_amdgcn_mfma_f32_16x16x32_bf16(a, b1, acc1, 0, 0, 0);
      __builtin_amdgcn_s_setprio(0);
    }
  }
  __syncthreads();

#pragma unroll
  for (int r = 0; r < 4; ++r) {
    red[wv * 529 + (lh * 4 + r) * 33 + l15] = acc0[r];
    red[wv * 529 + (lh * 4 + r) * 33 + 16 + l15] = acc1[r];
  }
  __syncthreads();
  if (tid < 512) {
    int row = tid >> 5, d = tid & 31;
    float s = 0.f;
#pragma unroll
    for (int w = 0; w < 16; ++w) s += red[w * 529 + row * 33 + d];
    s *= is_arr[row];
    ao[((size_t)bh * S_ + q0 + row) * 32 + d] = f2bf1(s);
  }
}

// ---------------- K4: output projection ----------------
__global__ __launch_bounds__(256) void k_proj(const unsigned short* __restrict__ wbf,
                                              const unsigned short* __restrict__ ao,
                                              float* __restrict__ out) {
  int b = blockIdx.z;
  int m0 = blockIdx.y * 64, n0 = blockIdx.x * 64;
  int tid = threadIdx.x, lane = tid & 63, wid = tid >> 6;
  int l15 = lane & 15, lh = lane >> 4;
  int wm = (wid >> 1) * 32, wn = (wid & 1) * 32;
  const unsigned short* aob = ao + (size_t)b * H_ * S_ * 32;
  f32x4 acc[2][2] = {};
  int mA = m0 + wm + l15;
  int nB = n0 + wn + l15;
  for (int k0 = 0; k0 < C_; k0 += 32) {
    int kk = k0 + lh * 8;
    int hh = kk >> 5;
    int dd = kk & 31;
    short8 a0 = *(const short8*)(wbf + (size_t)mA * C_ + kk);
    short8 a1 = *(const short8*)(wbf + (size_t)(mA + 16) * C_ + kk);
    short8 b0 = *(const short8*)(aob + ((size_t)hh * S_ + nB) * 32 + dd);
    short8 b1 = *(const short8*)(aob + ((size_t)hh * S_ + nB + 16) * 32 + dd);
    acc[0][0] = __builtin_amdgcn_mfma_f32_16x16x32_bf16(a0, b0, acc[0][0], 0, 0, 0);
    acc[0][1] = __builtin_amdgcn_mfma_f32_16x16x32_bf16(a0, b1, acc[0][1], 0, 0, 0);
    acc[1][0] = __builtin_amdgcn_mfma_f32_16x16x32_bf16(a1, b0, acc[1][0], 0, 0, 0);
    acc[1][1] = __builtin_amdgcn_mfma_f32_16x16x32_bf16(a1, b1, acc[1][1], 0, 0, 0);
  }
  float* ob = out + (size_t)b * C_ * S_;
#pragma unroll
  for (int i = 0; i < 2; ++i)
#pragma unroll
    for (int j = 0; j < 2; ++j)
#pragma unroll
      for (int r = 0; r < 4; ++r) {
        int row = m0 + wm + i * 16 + lh * 4 + r;
        int col = n0 + wn + j * 16 + l15;
        ob[(size_t)row * S_ + col] = acc[i][j][r];
      }
}

extern "C" void kernel_launch(void* const* d_in, const int* in_sizes, int n_in,
                              void* d_out, int out_size, void* d_ws, size_t ws_size,
                              hipStream_t stream) {
  const float* x = (const float*)d_in[0];
  const float* wqkv = (const float*)d_in[1];
  const float* wdw = (const float*)d_in[2];
  const float* wproj = (const float*)d_in[3];
  const float* temp = (const float*)d_in[4];
  float* out = (float*)d_out;

  char* ws = (char*)d_ws;
  size_t off = 0;
  auto alloc = [&](size_t bytes) -> void* {
    void* p = ws + off;
    off += (bytes + 255) & ~(size_t)255;
    return p;
  };
  unsigned short* wq_hi    = (unsigned short*)alloc((size_t)O3_ * C_ * 2);
  unsigned short* wq_lo    = (unsigned short*)alloc((size_t)O3_ * C_ * 2);
  unsigned short* wproj_bf = (unsigned short*)alloc((size_t)C_ * C_ * 2);
  unsigned short* q_hi     = (unsigned short*)alloc((size_t)B_ * H_ * S_ * 32 * 2);
  unsigned short* q_lo     = (unsigned short*)alloc((size_t)B_ * H_ * S_ * 32 * 2);
  unsigned short* k_hi     = (unsigned short*)alloc((size_t)B_ * H_ * S_ * 32 * 2);
  unsigned short* k_lo     = (unsigned short*)alloc((size_t)B_ * H_ * S_ * 32 * 2);
  unsigned short* vt       = (unsigned short*)alloc((size_t)B_ * H_ * 32 * S_ * 2);
  unsigned short* ao       = (unsigned short*)alloc((size_t)B_ * H_ * S_ * 32 * 2);

  (void)hipFuncSetAttribute(reinterpret_cast<const void*>(k_attn),
                            hipFuncAttributeMaxDynamicSharedMemorySize, (int)K3_LDS_BYTES);

  k_convw<<<dim3((O3_ * C_ + 255) / 256), dim3(256), 0, stream>>>(wqkv, wproj, wq_hi, wq_lo, wproj_bf);
  k_qkvf<<<dim3(S_ / 64, H_, B_), dim3(512), 0, stream>>>(wq_hi, wq_lo, x, wdw, temp,
                                                          q_hi, q_lo, k_hi, k_lo, vt);
  k_attn<<<dim3(B_ * H_ * (S_ / QT)), dim3(1024), K3_LDS_BYTES, stream>>>(q_hi, q_lo, k_hi, k_lo, vt, ao);
  k_proj<<<dim3(S_ / 64, C_ / 64, B_), dim3(256), 0, stream>>>(wproj_bf, ao, out);
}